// Round 2
// baseline (16750.496 us; speedup 1.0000x reference)
//
#include <hip/hip_runtime.h>
#include <hip/hip_bf16.h>

typedef unsigned short u16;
typedef __attribute__((ext_vector_type(8))) short short8;
typedef __attribute__((ext_vector_type(4))) float f32x4;

#define NB 256          // main kernel grid blocks
#define NT 512          // main kernel threads (8 waves)
#define TS 128          // time steps
#define BATCH 256
#define K0 1280         // 256 (x) + 1024 (h0)
#define K1 1280         // 1024 (h0) + 256 (h1)
#define LDK 136         // 128 + 8 bf16 pad

// d_out offsets (floats): [out][h_n0][h_n1][c_n0][c_n1]
#define OFF_H0  786432
#define OFF_H1  1048576
#define OFF_C0  1114112
#define OFF_C1  1376256

// ws offsets (bytes)
#define WSO_W0T  0
#define WSO_W1T  (WSO_W0T + 4096*1280*2)
#define WSO_B0   (WSO_W1T + 1024*1280*2)
#define WSO_B1   (WSO_B0  + 4096*4)
#define WSO_A0   (WSO_B1  + 1024*4)
#define WSO_A1   (WSO_A0  + 2*256*1280*2)
#define WSO_HSEQ (WSO_A1  + 2*256*1280*2)
#define WSO_BAR  (WSO_HSEQ + 128*256*256*4)
// barrier region: 256 flag slots x 16 dwords (64B apart) + 16 dwords release
#define BAR_DW   (256*16 + 16)
#define WS_NEED  (WSO_BAR + BAR_DW*4)

struct MP {
  const float* x;       // (256,128,256) fp32
  const u16*  W0T;      // [4096][1280] bf16, row n=h*4+g, cols k (0..255 = x, 256..1279 = h0)
  const u16*  W1T;      // [1024][1280] bf16, cols k (0..1023 = h0, 1024..1279 = h1)
  const float* b0;      // [4096] bx0+bh0 packed n=h*4+g
  const float* b1;      // [1024]
  u16*  A0;             // 2 x [256][1280] bf16 operand panels, parity t&1
  u16*  A1;             // 2 x [256][1280]
  float* hseq;          // [128][256][256] h1 sequence fp32
  float* out;           // d_out
  unsigned* flags;      // [256] arrival flags, 16-dword stride
  unsigned* rel;        // release counter
};

__device__ __forceinline__ float sigm(float x){ return 1.f/(1.f+__expf(-x)); }
__device__ __forceinline__ float tanh_(float x){
  float t = __expf(-2.f*fabsf(x));
  float r = (1.f - t)/(1.f + t);
  return x < 0.f ? -r : r;
}
__device__ __forceinline__ u16 f2b(float v){
  __hip_bfloat16 h = __float2bfloat16(v);
  return *reinterpret_cast<u16*>(&h);
}

// ---------------- prologue kernels ----------------

__global__ void k_pack(const float* __restrict__ Wx, const float* __restrict__ Wh,
                       u16* __restrict__ dst, int KX, int H){
  __shared__ float tile[64][65];
  int k0 = blockIdx.x*64, h0 = blockIdx.y*64, g = blockIdx.z;
  int tid = threadIdx.x;
  int c = tid & 63;
  for (int r = tid >> 6; r < 64; r += 4) {
    int k = k0 + r;
    float v = (k < KX) ? Wx[((size_t)g*KX + k)*H + h0 + c]
                       : Wh[((size_t)g*H + (k-KX))*H + h0 + c];
    tile[r][c] = v;
  }
  __syncthreads();
  for (int cc = tid; cc < 512; cc += 256) {
    int hl = cc >> 3, seg = cc & 7;
    union { u16 u[8]; short8 v; } pk;
#pragma unroll
    for (int j = 0; j < 8; ++j) pk.u[j] = f2b(tile[seg*8 + j][hl]);
    *(short8*)&dst[((size_t)(h0+hl)*4 + g)*1280 + k0 + seg*8] = pk.v;
  }
}

__global__ void k_bias(const float* __restrict__ bx0, const float* __restrict__ bh0,
                       const float* __restrict__ bx1, const float* __restrict__ bh1,
                       float* __restrict__ b0, float* __restrict__ b1){
  int n = blockIdx.x*256 + threadIdx.x;
  if (n < 4096) { int h = n >> 2, g = n & 3; b0[n] = bx0[g*1024 + h] + bh0[g*1024 + h]; }
  if (n < 1024) { int h = n >> 2, g = n & 3; b1[n] = bx1[g*256 + h] + bh1[g*256 + h]; }
}

__global__ void k_init(u16* __restrict__ A0, u16* __restrict__ A1,
                       float* __restrict__ out, unsigned* __restrict__ barbase){
  int i = blockIdx.x*256 + threadIdx.x;          // up to 655360
  if (i < 2*256*1280) { A0[i] = 0; A1[i] = 0; }
  if (i < 262144) out[OFF_C0 + i] = 0.f;
  if (i < 65536)  out[OFF_C1 + i] = 0.f;
  if (i < BAR_DW) barbase[i] = 0u;
}

__global__ void k_init2(const float* __restrict__ x, u16* __restrict__ A0){
  int i = blockIdx.x*256 + threadIdx.x;          // 65536
  int b = i >> 8, f = i & 255;
  A0[b*1280 + f] = f2b(x[(size_t)b*32768 + f]);  // x[:,0,:]
}

// ---------------- grid barrier (flag-based, no serialized RMW) ----------------
__device__ __forceinline__ void gbar(const MP& p, unsigned gen){
  __syncthreads();
  if (blockIdx.x == 0) {
    int tid = threadIdx.x;
    if (tid >= 1 && tid < 256) {
      while (__hip_atomic_load(&p.flags[tid*16], __ATOMIC_ACQUIRE,
                               __HIP_MEMORY_SCOPE_AGENT) < gen)
        __builtin_amdgcn_s_sleep(2);
    }
    __syncthreads();
    __threadfence();
    if (tid == 0)
      __hip_atomic_store(p.rel, gen, __ATOMIC_RELEASE, __HIP_MEMORY_SCOPE_AGENT);
    __syncthreads();
  } else {
    if (threadIdx.x == 0) {
      __threadfence();
      __hip_atomic_store(&p.flags[blockIdx.x*16], gen, __ATOMIC_RELEASE,
                         __HIP_MEMORY_SCOPE_AGENT);
      while (__hip_atomic_load(p.rel, __ATOMIC_ACQUIRE,
                               __HIP_MEMORY_SCOPE_AGENT) < gen)
        __builtin_amdgcn_s_sleep(2);
      __threadfence();
    }
    __syncthreads();
  }
}

// ---------------- main cooperative kernel ----------------
__device__ void phase0(const MP& p, int t, char* smem){
  int bid = blockIdx.x;
  int local = bid >> 3, xcd = bid & 7;
  int mt = local >> 3;                  // 0..3
  int nt = xcd*8 + (local & 7);         // 0..63
  int m0 = mt*64, n0 = nt*64;
  u16* As = (u16*)smem;                 // [64][LDK]
  u16* Bs = (u16*)smem + 64*LDK;        // [64][LDK]
  const u16* A = p.A0 + (size_t)(t & 1) * BATCH * K0;
  const u16* B = p.W0T;
  int tid = threadIdx.x, lane = tid & 63, wid = tid >> 6;
  int wm = wid >> 2, wn = wid & 3;      // 2 x 4
  int lrow = lane & 15, kgrp = lane >> 4;
  f32x4 acc0 = {0.f,0.f,0.f,0.f}, acc1 = {0.f,0.f,0.f,0.f};
  for (int kt = 0; kt < K0/128; ++kt) {
    int kk0 = kt*128;
    for (int c = tid; c < 1024; c += NT) {
      int r = c >> 4, s = c & 15;
      *(short8*)&As[r*LDK + s*8] = *(const short8*)&A[(m0 + r)*K0 + kk0 + s*8];
      *(short8*)&Bs[r*LDK + s*8] = *(const short8*)&B[(n0 + r)*K0 + kk0 + s*8];
    }
    __syncthreads();
#pragma unroll
    for (int kk = 0; kk < 4; ++kk) {
      short8 bv = *(const short8*)&Bs[(wn*16 + lrow)*LDK + kk*32 + kgrp*8];
      short8 a0 = *(const short8*)&As[(wm*32 + lrow)*LDK + kk*32 + kgrp*8];
      short8 a1 = *(const short8*)&As[(wm*32 + 16 + lrow)*LDK + kk*32 + kgrp*8];
      acc0 = __builtin_amdgcn_mfma_f32_16x16x32_bf16(a0, bv, acc0, 0, 0, 0);
      acc1 = __builtin_amdgcn_mfma_f32_16x16x32_bf16(a1, bv, acc1, 0, 0, 0);
    }
    __syncthreads();
  }
  float* gl = (float*)smem;
#pragma unroll
  for (int r = 0; r < 4; ++r) {
    gl[(wm*32 + kgrp*4 + r)*68 + wn*16 + lrow]      = acc0[r];
    gl[(wm*32 + 16 + kgrp*4 + r)*68 + wn*16 + lrow] = acc1[r];
  }
  __syncthreads();
  float* c0s = p.out + OFF_C0;
  u16* A0n = p.A0 + (size_t)((t+1) & 1) * BATCH * K0;
  u16* A1c = p.A1 + (size_t)(t & 1) * BATCH * K1;
  for (int e = tid; e < 1024; e += NT) {
    int bl = e >> 4, hl = e & 15;
    int b = m0 + bl, h = (n0 >> 2) + hl;
    float gi = gl[bl*68 + hl*4+0] + p.b0[n0 + hl*4+0];
    float gf = gl[bl*68 + hl*4+1] + p.b0[n0 + hl*4+1];
    float go = gl[bl*68 + hl*4+2] + p.b0[n0 + hl*4+2];
    float gc = gl[bl*68 + hl*4+3] + p.b0[n0 + hl*4+3];
    float cp = c0s[b*1024 + h];
    float cn = sigm(gf)*cp + sigm(gi)*tanh_(gc);
    float hn = sigm(go)*tanh_(cn);
    c0s[b*1024 + h] = cn;
    u16 hb = f2b(hn);
    A0n[b*K0 + 256 + h] = hb;
    A1c[b*K1 + h] = hb;
    if (t == TS-1) p.out[OFF_H0 + b*1024 + h] = hn;
  }
}

__device__ void phase1(const MP& p, int t, char* smem){
  int bid = blockIdx.x;
  int local = bid >> 3, xcd = bid & 7;
  int mt = local >> 2;                  // 0..7
  int nt = xcd*4 + (local & 3);         // 0..31
  int m0 = mt*32, n0 = nt*32;
  u16* As = (u16*)smem;
  u16* Bs = (u16*)smem + 32*LDK;
  const u16* A = p.A1 + (size_t)(t & 1) * BATCH * K1;
  const u16* B = p.W1T;
  int tid = threadIdx.x, lane = tid & 63, wid = tid >> 6;
  int lrow = lane & 15, kgrp = lane >> 4;
  int wm = wid >> 1, wn = wid & 1;
  f32x4 acc = {0.f,0.f,0.f,0.f};
  for (int kt = 0; kt < K1/128; ++kt) {
    int kk0 = kt*128;
    for (int c = tid; c < 1024; c += NT) {
      int cc = c & 511; int r = cc >> 4, s = cc & 15;
      if (c < 512) *(short8*)&As[r*LDK + s*8] = *(const short8*)&A[(m0 + r)*K1 + kk0 + s*8];
      else         *(short8*)&Bs[r*LDK + s*8] = *(const short8*)&B[(n0 + r)*K1 + kk0 + s*8];
    }
    __syncthreads();
    if (wid < 4) {
#pragma unroll
      for (int kk = 0; kk < 4; ++kk) {
        short8 av = *(const short8*)&As[(wm*16 + lrow)*LDK + kk*32 + kgrp*8];
        short8 bv = *(const short8*)&Bs[(wn*16 + lrow)*LDK + kk*32 + kgrp*8];
        acc = __builtin_amdgcn_mfma_f32_16x16x32_bf16(av, bv, acc, 0, 0, 0);
      }
    }
    __syncthreads();
  }
  float* gl = (float*)smem;             // [32][36]
  if (wid < 4) {
#pragma unroll
    for (int r = 0; r < 4; ++r)
      gl[(wm*16 + kgrp*4 + r)*36 + wn*16 + lrow] = acc[r];
  }
  __syncthreads();
  float* c1s = p.out + OFF_C1;
  u16* A1n = p.A1 + (size_t)((t+1) & 1) * BATCH * K1;
  if (tid < 256) {
    int bl = tid >> 3, hl = tid & 7;
    int b = m0 + bl, h = (n0 >> 2) + hl;
    float gi = gl[bl*36 + hl*4+0] + p.b1[n0 + hl*4+0];
    float gf = gl[bl*36 + hl*4+1] + p.b1[n0 + hl*4+1];
    float go = gl[bl*36 + hl*4+2] + p.b1[n0 + hl*4+2];
    float gc = gl[bl*36 + hl*4+3] + p.b1[n0 + hl*4+3];
    float cp = c1s[b*256 + h];
    float cn = sigm(gf)*cp + sigm(gi)*tanh_(gc);
    float hn = sigm(go)*tanh_(cn);
    c1s[b*256 + h] = cn;
    A1n[b*K1 + 1024 + h] = f2b(hn);
    p.hseq[((size_t)t*256 + b)*256 + h] = hn;
    if (t == TS-1) p.out[OFF_H1 + b*256 + h] = hn;
  }
  if (t + 1 < TS) {
    int gid = bid*NT + tid;
    if (gid < 65536) {
      int b = gid >> 8, f = gid & 255;
      u16* A0n = p.A0 + (size_t)((t+1) & 1) * BATCH * K0;
      A0n[b*K0 + f] = f2b(p.x[(size_t)b*32768 + (t+1)*256 + f]);
    }
  }
}

__global__ __launch_bounds__(NT) void k_main(MP p){
  __shared__ __attribute__((aligned(16))) char smem[2*64*LDK*2];  // 34816 B
  for (int t = 0; t < TS; ++t) {
    phase0(p, t, smem);
    gbar(p, (unsigned)(2*t + 1));
    phase1(p, t, smem);
    gbar(p, (unsigned)(2*t + 2));
  }
}

// ---------------- final projection ----------------
__global__ void k_final(const float* __restrict__ hseq, const float* __restrict__ Wout,
                        const float* __restrict__ bout, float* __restrict__ out){
  __shared__ float Ws[1536];
  __shared__ float bs[12];
  for (int i = threadIdx.x; i < 1536; i += 256) Ws[i] = Wout[i];
  if (threadIdx.x < 12) bs[threadIdx.x] = bout[threadIdx.x];
  __syncthreads();
  int gid = blockIdx.x*256 + threadIdx.x;
  int b = gid >> 8, ii = gid & 255;
  const float* src = hseq + ((size_t)(ii >> 1)*256 + b)*256 + (ii & 1)*128;
  float acc[12];
#pragma unroll
  for (int k = 0; k < 12; ++k) acc[k] = bs[k];
  for (int j = 0; j < 128; j += 4) {
    float4 v = *(const float4*)&src[j];
#pragma unroll
    for (int k = 0; k < 12; ++k)
      acc[k] += v.x*Ws[(j+0)*12+k] + v.y*Ws[(j+1)*12+k] + v.z*Ws[(j+2)*12+k] + v.w*Ws[(j+3)*12+k];
  }
  float* dst = out + (size_t)b*3072 + ii*12;
#pragma unroll
  for (int k = 0; k < 12; ++k) dst[k] = acc[k];
}

extern "C" void kernel_launch(void* const* d_in, const int* in_sizes, int n_in,
                              void* d_out, int out_size, void* d_ws, size_t ws_size,
                              hipStream_t stream) {
  if (ws_size < (size_t)WS_NEED) return;
  const float* x    = (const float*)d_in[0];
  const float* Wx0  = (const float*)d_in[1];
  const float* bx0  = (const float*)d_in[2];
  const float* Wh0  = (const float*)d_in[3];
  const float* bh0  = (const float*)d_in[4];
  const float* Wx1  = (const float*)d_in[5];
  const float* bx1  = (const float*)d_in[6];
  const float* Wh1  = (const float*)d_in[7];
  const float* bh1  = (const float*)d_in[8];
  const float* Wout = (const float*)d_in[9];
  const float* bout = (const float*)d_in[10];

  char* ws = (char*)d_ws;
  u16*   W0T  = (u16*)  (ws + WSO_W0T);
  u16*   W1T  = (u16*)  (ws + WSO_W1T);
  float* b0   = (float*)(ws + WSO_B0);
  float* b1   = (float*)(ws + WSO_B1);
  u16*   A0   = (u16*)  (ws + WSO_A0);
  u16*   A1   = (u16*)  (ws + WSO_A1);
  float* hseq = (float*)(ws + WSO_HSEQ);
  unsigned* barbase = (unsigned*)(ws + WSO_BAR);
  float* out = (float*)d_out;

  k_pack<<<dim3(20,16,4), 256, 0, stream>>>(Wx0, Wh0, W0T, 256, 1024);
  k_pack<<<dim3(20, 4,4), 256, 0, stream>>>(Wx1, Wh1, W1T, 1024, 256);
  k_bias<<<16, 256, 0, stream>>>(bx0, bh0, bx1, bh1, b0, b1);
  k_init<<<2560, 256, 0, stream>>>(A0, A1, out, barbase);
  k_init2<<<256, 256, 0, stream>>>(x, A0);

  MP p;
  p.x = x; p.W0T = W0T; p.W1T = W1T; p.b0 = b0; p.b1 = b1;
  p.A0 = A0; p.A1 = A1; p.hseq = hseq; p.out = out;
  p.flags = barbase; p.rel = barbase + 256*16;
  void* kargs[] = { (void*)&p };
  hipLaunchCooperativeKernel((const void*)k_main, dim3(NB), dim3(NT), kargs, 0, stream);

  k_final<<<256, 256, 0, stream>>>(hseq, Wout, bout, out);
}

// Round 3
// 11763.152 us; speedup vs baseline: 1.4240x; 1.4240x over previous
//
#include <hip/hip_runtime.h>
#include <hip/hip_bf16.h>

typedef unsigned short u16;
typedef __attribute__((ext_vector_type(8))) short short8;
typedef __attribute__((ext_vector_type(4))) float f32x4;

#define NB 256          // main kernel grid blocks
#define NT 512          // threads (8 waves)
#define TS 128
#define BATCH 256
#define K0 1280         // 256 (x) + 1024 (h0)
#define K1 1280         // 1024 (h0) + 256 (h1)
#define LDK 136         // 128 + 8 bf16 pad

// d_out offsets (floats): [out][h_n0][h_n1][c_n0][c_n1]
#define OFF_H0  786432
#define OFF_H1  1048576
#define OFF_C0  1114112
#define OFF_C1  1376256

// ws offsets (bytes)
#define WSO_W0T  0
#define WSO_W1T  (WSO_W0T + 4096*1280*2)
#define WSO_B0   (WSO_W1T + 1024*1280*2)
#define WSO_B1   (WSO_B0  + 4096*4)
#define WSO_A0   (WSO_B1  + 1024*4)
#define WSO_A1   (WSO_A0  + 2*256*1280*2)
#define WSO_HSEQ (WSO_A1  + 2*256*1280*2)
#define WSO_BAR  (WSO_HSEQ + 128*256*256*4)
// barrier region: arr 8x16 dw | root 16 dw | rel 8x16 dw
#define BAR_DW   (8*16 + 16 + 8*16)
#define WS_NEED  (WSO_BAR + BAR_DW*4)

struct MP {
  const float* x;
  const u16*  W0T;      // [4096][1280] bf16, row n=h*4+g
  const u16*  W1T;      // [1024][1280] bf16
  const float* b0;      // [4096]
  const float* b1;      // [1024]
  u16*  A0;             // 2 x [256][1280] operand panels, parity t&1
  u16*  A1;             // 2 x [256][1280]
  float* hseq;          // [128][256][256]
  float* out;
  unsigned* arr;        // 8 lines x 16 dw
  unsigned* root;       // 1 line
  unsigned* rel;        // 8 lines x 16 dw
};

__device__ __forceinline__ float sigm(float x){ return 1.f/(1.f+__expf(-x)); }
__device__ __forceinline__ float tanh_(float x){
  float t = __expf(-2.f*fabsf(x));
  float r = (1.f - t)/(1.f + t);
  return x < 0.f ? -r : r;
}
__device__ __forceinline__ u16 f2b(float v){
  __hip_bfloat16 h = __float2bfloat16(v);
  return *reinterpret_cast<u16*>(&h);
}

// ---------------- prologue kernels ----------------

__global__ void k_pack(const float* __restrict__ Wx, const float* __restrict__ Wh,
                       u16* __restrict__ dst, int KX, int H){
  __shared__ float tile[64][65];
  int k0 = blockIdx.x*64, h0 = blockIdx.y*64, g = blockIdx.z;
  int tid = threadIdx.x;
  int c = tid & 63;
  for (int r = tid >> 6; r < 64; r += 4) {
    int k = k0 + r;
    float v = (k < KX) ? Wx[((size_t)g*KX + k)*H + h0 + c]
                       : Wh[((size_t)g*H + (k-KX))*H + h0 + c];
    tile[r][c] = v;
  }
  __syncthreads();
  for (int cc = tid; cc < 512; cc += 256) {
    int hl = cc >> 3, seg = cc & 7;
    union { u16 u[8]; short8 v; } pk;
#pragma unroll
    for (int j = 0; j < 8; ++j) pk.u[j] = f2b(tile[seg*8 + j][hl]);
    *(short8*)&dst[((size_t)(h0+hl)*4 + g)*1280 + k0 + seg*8] = pk.v;
  }
}

__global__ void k_bias(const float* __restrict__ bx0, const float* __restrict__ bh0,
                       const float* __restrict__ bx1, const float* __restrict__ bh1,
                       float* __restrict__ b0, float* __restrict__ b1){
  int n = blockIdx.x*256 + threadIdx.x;
  if (n < 4096) { int h = n >> 2, g = n & 3; b0[n] = bx0[g*1024 + h] + bh0[g*1024 + h]; }
  if (n < 1024) { int h = n >> 2, g = n & 3; b1[n] = bx1[g*256 + h] + bh1[g*256 + h]; }
}

__global__ void k_init(u16* __restrict__ A0, u16* __restrict__ A1,
                       float* __restrict__ out, unsigned* __restrict__ barbase){
  int i = blockIdx.x*256 + threadIdx.x;
  if (i < 2*256*1280) { A0[i] = 0; A1[i] = 0; }
  if (i < 262144) out[OFF_C0 + i] = 0.f;
  if (i < 65536)  out[OFF_C1 + i] = 0.f;
  if (i < BAR_DW) barbase[i] = 0u;
}

__global__ void k_init2(const float* __restrict__ x, u16* __restrict__ A0){
  int i = blockIdx.x*256 + threadIdx.x;          // 65536
  int b = i >> 8, f = i & 255;
  A0[b*1280 + f] = f2b(x[(size_t)b*32768 + f]);  // x[:,0,:]
}

// ---------------- hierarchical grid barrier ----------------
__device__ __forceinline__ void gbar(const MP& p, unsigned gen){
  __syncthreads();
  if (threadIdx.x == 0) {
    int xcd = blockIdx.x & 7;
    __threadfence();
    unsigned a = __hip_atomic_fetch_add(&p.arr[xcd*16], 1u, __ATOMIC_RELEASE,
                                        __HIP_MEMORY_SCOPE_AGENT);
    if (a == gen*32u - 1u) {           // last arriver in this XCD
      unsigned r = __hip_atomic_fetch_add(p.root, 1u, __ATOMIC_ACQ_REL,
                                          __HIP_MEMORY_SCOPE_AGENT);
      if (r == gen*8u - 1u) {          // last XCD
#pragma unroll
        for (int i = 0; i < 8; ++i)
          __hip_atomic_store(&p.rel[i*16], gen, __ATOMIC_RELEASE,
                             __HIP_MEMORY_SCOPE_AGENT);
      }
    }
    while (__hip_atomic_load(&p.rel[xcd*16], __ATOMIC_ACQUIRE,
                             __HIP_MEMORY_SCOPE_AGENT) < gen)
      __builtin_amdgcn_s_sleep(1);
    __threadfence();
  }
  __syncthreads();
}

// ---------------- main cooperative kernel ----------------
// phase0: gates0(256x4096) = A0[t&1] @ W0T^T + b0, fused layer-0 cell.
// 128 jobs, tile 64x128 (bids 0..127). 8 waves 2x4, wave-tile 32x32.
__device__ void phase0(const MP& p, int t, char* smem){
  int bid = blockIdx.x;
  int xcd = bid & 7, local = (bid >> 3) & 3, mt = bid >> 5;
  int nt = xcd*4 + local;               // 0..31
  int m0 = mt*64, n0 = nt*128;
  u16* As = (u16*)smem;                 // [64][LDK]
  u16* Bs = (u16*)smem + 64*LDK;        // [128][LDK]
  const u16* A = p.A0 + (size_t)(t & 1) * BATCH * K0;
  const u16* B = p.W0T;
  int tid = threadIdx.x, lane = tid & 63, wid = tid >> 6;
  int wm = wid >> 2, wn = wid & 3;
  int lrow = lane & 15, kgrp = lane >> 4;
  f32x4 acc00 = {0,0,0,0}, acc01 = {0,0,0,0}, acc10 = {0,0,0,0}, acc11 = {0,0,0,0};
  for (int kt = 0; kt < K0/128; ++kt) {
    int kk0 = kt*128;
    for (int c = tid; c < 3072; c += NT) {
      if (c < 1024) {
        int r = c >> 4, s = c & 15;
        *(short8*)&As[r*LDK + s*8] = *(const short8*)&A[(m0 + r)*K0 + kk0 + s*8];
      } else {
        int d = c - 1024, r = d >> 4, s = d & 15;
        *(short8*)&Bs[r*LDK + s*8] = *(const short8*)&B[(n0 + r)*K0 + kk0 + s*8];
      }
    }
    __syncthreads();
#pragma unroll
    for (int kk = 0; kk < 4; ++kk) {
      short8 a0 = *(const short8*)&As[(wm*32 + lrow)*LDK + kk*32 + kgrp*8];
      short8 a1 = *(const short8*)&As[(wm*32 + 16 + lrow)*LDK + kk*32 + kgrp*8];
      short8 b0 = *(const short8*)&Bs[(wn*32 + lrow)*LDK + kk*32 + kgrp*8];
      short8 b1 = *(const short8*)&Bs[(wn*32 + 16 + lrow)*LDK + kk*32 + kgrp*8];
      acc00 = __builtin_amdgcn_mfma_f32_16x16x32_bf16(a0, b0, acc00, 0, 0, 0);
      acc01 = __builtin_amdgcn_mfma_f32_16x16x32_bf16(a0, b1, acc01, 0, 0, 0);
      acc10 = __builtin_amdgcn_mfma_f32_16x16x32_bf16(a1, b0, acc10, 0, 0, 0);
      acc11 = __builtin_amdgcn_mfma_f32_16x16x32_bf16(a1, b1, acc11, 0, 0, 0);
    }
    __syncthreads();
  }
  float* gl = (float*)smem;             // [64][132]
#pragma unroll
  for (int r = 0; r < 4; ++r) {
    gl[(wm*32      + kgrp*4 + r)*132 + wn*32      + lrow] = acc00[r];
    gl[(wm*32      + kgrp*4 + r)*132 + wn*32 + 16 + lrow] = acc01[r];
    gl[(wm*32 + 16 + kgrp*4 + r)*132 + wn*32      + lrow] = acc10[r];
    gl[(wm*32 + 16 + kgrp*4 + r)*132 + wn*32 + 16 + lrow] = acc11[r];
  }
  __syncthreads();
  float* c0s = p.out + OFF_C0;
  u16* A0n = p.A0 + (size_t)((t+1) & 1) * BATCH * K0;
  u16* A1c = p.A1 + (size_t)(t & 1) * BATCH * K1;
  for (int e = tid; e < 2048; e += NT) {
    int bl = e >> 5, hl = e & 31;
    int b = m0 + bl, h = nt*32 + hl;
    float gi = gl[bl*132 + hl*4+0] + p.b0[n0 + hl*4+0];
    float gf = gl[bl*132 + hl*4+1] + p.b0[n0 + hl*4+1];
    float go = gl[bl*132 + hl*4+2] + p.b0[n0 + hl*4+2];
    float gc = gl[bl*132 + hl*4+3] + p.b0[n0 + hl*4+3];
    float cp = c0s[b*1024 + h];
    float cn = sigm(gf)*cp + sigm(gi)*tanh_(gc);
    float hn = sigm(go)*tanh_(cn);
    c0s[b*1024 + h] = cn;
    u16 hb = f2b(hn);
    A0n[b*K0 + 256 + h] = hb;           // layer0 operand @ t+1
    A1c[b*K1 + h] = hb;                 // layer1 operand @ t (consumed next macro-step)
    if (t == TS-1) p.out[OFF_H0 + b*1024 + h] = hn;
  }
}

// phase1: gates1(256x1024) = A1[t&1] @ W1T^T + b1, fused layer-1 cell.
// 64 jobs, tile 64x64 (bids 128..191). 8 waves 2x4, wave-tile 32x16.
__device__ void phase1(const MP& p, int t, char* smem){
  int j = blockIdx.x - 128;
  int xcd = j & 7, local = (j >> 3) & 1, mt = j >> 4;
  int ntp = xcd*2 + local;              // 0..15
  int m0 = mt*64, n0 = ntp*64;
  u16* As = (u16*)smem;                 // [64][LDK]
  u16* Bs = (u16*)smem + 64*LDK;        // [64][LDK]
  const u16* A = p.A1 + (size_t)(t & 1) * BATCH * K1;
  const u16* B = p.W1T;
  int tid = threadIdx.x, lane = tid & 63, wid = tid >> 6;
  int wm = wid >> 2, wn = wid & 3;
  int lrow = lane & 15, kgrp = lane >> 4;
  f32x4 acc0 = {0,0,0,0}, acc1 = {0,0,0,0};
  for (int kt = 0; kt < K1/128; ++kt) {
    int kk0 = kt*128;
    for (int c = tid; c < 2048; c += NT) {
      int cc = c & 1023; int r = cc >> 4, s = cc & 15;
      if (c < 1024) *(short8*)&As[r*LDK + s*8] = *(const short8*)&A[(m0 + r)*K1 + kk0 + s*8];
      else          *(short8*)&Bs[r*LDK + s*8] = *(const short8*)&B[(n0 + r)*K1 + kk0 + s*8];
    }
    __syncthreads();
#pragma unroll
    for (int kk = 0; kk < 4; ++kk) {
      short8 bv = *(const short8*)&Bs[(wn*16 + lrow)*LDK + kk*32 + kgrp*8];
      short8 a0 = *(const short8*)&As[(wm*32 + lrow)*LDK + kk*32 + kgrp*8];
      short8 a1 = *(const short8*)&As[(wm*32 + 16 + lrow)*LDK + kk*32 + kgrp*8];
      acc0 = __builtin_amdgcn_mfma_f32_16x16x32_bf16(a0, bv, acc0, 0, 0, 0);
      acc1 = __builtin_amdgcn_mfma_f32_16x16x32_bf16(a1, bv, acc1, 0, 0, 0);
    }
    __syncthreads();
  }
  float* gl = (float*)smem;             // [64][68]
#pragma unroll
  for (int r = 0; r < 4; ++r) {
    gl[(wm*32      + kgrp*4 + r)*68 + wn*16 + lrow] = acc0[r];
    gl[(wm*32 + 16 + kgrp*4 + r)*68 + wn*16 + lrow] = acc1[r];
  }
  __syncthreads();
  float* c1s = p.out + OFF_C1;
  u16* A1n = p.A1 + (size_t)((t+1) & 1) * BATCH * K1;
  for (int e = tid; e < 1024; e += NT) {
    int bl = e >> 4, hl = e & 15;
    int b = m0 + bl, h = ntp*16 + hl;
    float gi = gl[bl*68 + hl*4+0] + p.b1[n0 + hl*4+0];
    float gf = gl[bl*68 + hl*4+1] + p.b1[n0 + hl*4+1];
    float go = gl[bl*68 + hl*4+2] + p.b1[n0 + hl*4+2];
    float gc = gl[bl*68 + hl*4+3] + p.b1[n0 + hl*4+3];
    float cp = c1s[b*256 + h];
    float cn = sigm(gf)*cp + sigm(gi)*tanh_(gc);
    float hn = sigm(go)*tanh_(cn);
    c1s[b*256 + h] = cn;
    A1n[b*K1 + 1024 + h] = f2b(hn);
    p.hseq[((size_t)t*256 + b)*256 + h] = hn;
    if (t == TS-1) p.out[OFF_H1 + b*256 + h] = hn;
  }
}

// spare blocks (192..255): pre-stage x_{tn} into A0 panel[tn&1]
__device__ void stage_x(const MP& p, int tn){
  int j = blockIdx.x - 192;             // 0..63
  u16* A0n = p.A0 + (size_t)(tn & 1) * BATCH * K0;
  for (int i = j*NT + threadIdx.x; i < 65536; i += 64*NT) {
    int b = i >> 8, f = i & 255;
    A0n[b*K0 + f] = f2b(p.x[(size_t)b*32768 + tn*256 + f]);
  }
}

__global__ __launch_bounds__(NT) void k_main(MP p){
  __shared__ __attribute__((aligned(16))) char smem[(64+128)*LDK*2];  // 52224 B
  int bid = blockIdx.x;
  for (int s = 0; s < TS; ++s) {
    if (bid < 128)        phase0(p, s, smem);          // layer0 @ t=s
    else if (bid < 192) { if (s >= 1) phase1(p, s-1, smem); }  // layer1 @ t=s-1
    else                { if (s+1 < TS) stage_x(p, s+1); }
    gbar(p, (unsigned)(s+1));
  }
  if (bid >= 128 && bid < 192) phase1(p, TS-1, smem);  // pipeline tail
}

// ---------------- final projection ----------------
__global__ void k_final(const float* __restrict__ hseq, const float* __restrict__ Wout,
                        const float* __restrict__ bout, float* __restrict__ out){
  __shared__ float Ws[1536];
  __shared__ float bs[12];
  for (int i = threadIdx.x; i < 1536; i += 256) Ws[i] = Wout[i];
  if (threadIdx.x < 12) bs[threadIdx.x] = bout[threadIdx.x];
  __syncthreads();
  int gid = blockIdx.x*256 + threadIdx.x;
  int b = gid >> 8, ii = gid & 255;
  const float* src = hseq + ((size_t)(ii >> 1)*256 + b)*256 + (ii & 1)*128;
  float acc[12];
#pragma unroll
  for (int k = 0; k < 12; ++k) acc[k] = bs[k];
  for (int j = 0; j < 128; j += 4) {
    float4 v = *(const float4*)&src[j];
#pragma unroll
    for (int k = 0; k < 12; ++k)
      acc[k] += v.x*Ws[(j+0)*12+k] + v.y*Ws[(j+1)*12+k] + v.z*Ws[(j+2)*12+k] + v.w*Ws[(j+3)*12+k];
  }
  float* dst = out + (size_t)b*3072 + ii*12;
#pragma unroll
  for (int k = 0; k < 12; ++k) dst[k] = acc[k];
}

extern "C" void kernel_launch(void* const* d_in, const int* in_sizes, int n_in,
                              void* d_out, int out_size, void* d_ws, size_t ws_size,
                              hipStream_t stream) {
  if (ws_size < (size_t)WS_NEED) return;
  const float* x    = (const float*)d_in[0];
  const float* Wx0  = (const float*)d_in[1];
  const float* bx0  = (const float*)d_in[2];
  const float* Wh0  = (const float*)d_in[3];
  const float* bh0  = (const float*)d_in[4];
  const float* Wx1  = (const float*)d_in[5];
  const float* bx1  = (const float*)d_in[6];
  const float* Wh1  = (const float*)d_in[7];
  const float* bh1  = (const float*)d_in[8];
  const float* Wout = (const float*)d_in[9];
  const float* bout = (const float*)d_in[10];

  char* ws = (char*)d_ws;
  u16*   W0T  = (u16*)  (ws + WSO_W0T);
  u16*   W1T  = (u16*)  (ws + WSO_W1T);
  float* b0   = (float*)(ws + WSO_B0);
  float* b1   = (float*)(ws + WSO_B1);
  u16*   A0   = (u16*)  (ws + WSO_A0);
  u16*   A1   = (u16*)  (ws + WSO_A1);
  float* hseq = (float*)(ws + WSO_HSEQ);
  unsigned* barbase = (unsigned*)(ws + WSO_BAR);
  float* out = (float*)d_out;

  k_pack<<<dim3(20,16,4), 256, 0, stream>>>(Wx0, Wh0, W0T, 256, 1024);
  k_pack<<<dim3(20, 4,4), 256, 0, stream>>>(Wx1, Wh1, W1T, 1024, 256);
  k_bias<<<16, 256, 0, stream>>>(bx0, bh0, bx1, bh1, b0, b1);
  k_init<<<2560, 256, 0, stream>>>(A0, A1, out, barbase);
  k_init2<<<256, 256, 0, stream>>>(x, A0);

  MP p;
  p.x = x; p.W0T = W0T; p.W1T = W1T; p.b0 = b0; p.b1 = b1;
  p.A0 = A0; p.A1 = A1; p.hseq = hseq; p.out = out;
  p.arr  = barbase;
  p.root = barbase + 8*16;
  p.rel  = barbase + 8*16 + 16;
  void* kargs[] = { (void*)&p };
  hipLaunchCooperativeKernel((const void*)k_main, dim3(NB), dim3(NT), kargs, 0, stream);

  k_final<<<256, 256, 0, stream>>>(hseq, Wout, bout, out);
}

// Round 4
// 3548.306 us; speedup vs baseline: 4.7207x; 3.3151x over previous
//
#include <hip/hip_runtime.h>
#include <hip/hip_bf16.h>

typedef unsigned short u16;
typedef unsigned int u32;
typedef unsigned long long u64;
typedef __attribute__((ext_vector_type(8))) short short8;
typedef __attribute__((ext_vector_type(4))) float f32x4;

#define NB 256          // main kernel grid blocks
#define NT 512          // threads (8 waves)
#define TS 128
#define BATCH 256
#define K0 1280         // 256 (x) + 1024 (h0)
#define K1 1280         // 1024 (h0) + 256 (h1)
#define LDK 136         // 128 + 8 bf16 pad

// d_out offsets (floats): [out][h_n0][h_n1][c_n0][c_n1]
#define OFF_H0  786432
#define OFF_H1  1048576
#define OFF_C0  1114112
#define OFF_C1  1376256

// ws offsets (bytes)
#define WSO_W0T  0
#define WSO_W1T  (WSO_W0T + 4096*1280*2)
#define WSO_B0   (WSO_W1T + 1024*1280*2)
#define WSO_B1   (WSO_B0  + 4096*4)
#define WSO_A0   (WSO_B1  + 1024*4)
#define WSO_A1   (WSO_A0  + 2*256*1280*2)
#define WSO_HSEQ (WSO_A1  + 2*256*1280*2)
#define WSO_BAR  (WSO_HSEQ + 128*256*256*4)
// barrier region: arr 8x16 dw | root 16 dw | rel 8x16 dw
#define BAR_DW   (8*16 + 16 + 8*16)
#define WS_NEED  (WSO_BAR + BAR_DW*4)

struct MP {
  const float* x;
  const u16*  W0T;      // [4096][1280] bf16, row n=h*4+g
  const u16*  W1T;      // [1024][1280] bf16
  const float* b0;      // [4096]
  const float* b1;      // [1024]
  u16*  A0;             // 2 x [256][1280] operand panels, parity t&1
  u16*  A1;             // 2 x [256][1280]
  float* hseq;          // [128][256][256]
  float* out;
  unsigned* arr;        // 8 lines x 16 dw
  unsigned* root;       // 1 line
  unsigned* rel;        // 8 lines x 16 dw
};

__device__ __forceinline__ float sigm(float x){ return 1.f/(1.f+__expf(-x)); }
__device__ __forceinline__ float tanh_(float x){
  float t = __expf(-2.f*fabsf(x));
  float r = (1.f - t)/(1.f + t);
  return x < 0.f ? -r : r;
}
__device__ __forceinline__ u16 f2b(float v){
  __hip_bfloat16 h = __float2bfloat16(v);
  return *reinterpret_cast<u16*>(&h);
}
// coherent (sc1, no-fence) accessors for cross-block data
__device__ __forceinline__ u64 ald64(const u16* p){
  return __hip_atomic_load((const u64*)p, __ATOMIC_RELAXED, __HIP_MEMORY_SCOPE_AGENT);
}
__device__ __forceinline__ void ast32(u16* p, u32 v){
  __hip_atomic_store((u32*)p, v, __ATOMIC_RELAXED, __HIP_MEMORY_SCOPE_AGENT);
}

// ---------------- prologue kernels ----------------

__global__ void k_pack(const float* __restrict__ Wx, const float* __restrict__ Wh,
                       u16* __restrict__ dst, int KX, int H){
  __shared__ float tile[64][65];
  int k0 = blockIdx.x*64, h0 = blockIdx.y*64, g = blockIdx.z;
  int tid = threadIdx.x;
  int c = tid & 63;
  for (int r = tid >> 6; r < 64; r += 4) {
    int k = k0 + r;
    float v = (k < KX) ? Wx[((size_t)g*KX + k)*H + h0 + c]
                       : Wh[((size_t)g*H + (k-KX))*H + h0 + c];
    tile[r][c] = v;
  }
  __syncthreads();
  for (int cc = tid; cc < 512; cc += 256) {
    int hl = cc >> 3, seg = cc & 7;
    union { u16 u[8]; short8 v; } pk;
#pragma unroll
    for (int j = 0; j < 8; ++j) pk.u[j] = f2b(tile[seg*8 + j][hl]);
    *(short8*)&dst[((size_t)(h0+hl)*4 + g)*1280 + k0 + seg*8] = pk.v;
  }
}

__global__ void k_bias(const float* __restrict__ bx0, const float* __restrict__ bh0,
                       const float* __restrict__ bx1, const float* __restrict__ bh1,
                       float* __restrict__ b0, float* __restrict__ b1){
  int n = blockIdx.x*256 + threadIdx.x;
  if (n < 4096) { int h = n >> 2, g = n & 3; b0[n] = bx0[g*1024 + h] + bh0[g*1024 + h]; }
  if (n < 1024) { int h = n >> 2, g = n & 3; b1[n] = bx1[g*256 + h] + bh1[g*256 + h]; }
}

__global__ void k_init(u16* __restrict__ A0, u16* __restrict__ A1,
                       float* __restrict__ out, unsigned* __restrict__ barbase){
  int i = blockIdx.x*256 + threadIdx.x;
  if (i < 2*256*1280) { A0[i] = 0; A1[i] = 0; }
  if (i < 262144) out[OFF_C0 + i] = 0.f;
  if (i < 65536)  out[OFF_C1 + i] = 0.f;
  if (i < BAR_DW) barbase[i] = 0u;
}

__global__ void k_init2(const float* __restrict__ x, u16* __restrict__ A0){
  int i = blockIdx.x*256 + threadIdx.x;          // 65536
  int b = i >> 8, f = i & 255;
  A0[b*1280 + f] = f2b(x[(size_t)b*32768 + f]);  // x[:,0,:]
}

// ---------------- hierarchical grid barrier (all relaxed, NO fences) ------
// Producer-side ordering: __syncthreads drains each wave's vmem (incl. sc1
// stores -> acked at coherence point). Consumer-side: control dependence on
// rel observation; cross-block data is read with sc1 loads (no stale cache).
__device__ __forceinline__ void gbar(const MP& p, unsigned gen){
  __syncthreads();
  if (threadIdx.x == 0) {
    int xcd = blockIdx.x & 7;
    unsigned a = __hip_atomic_fetch_add(&p.arr[xcd*16], 1u, __ATOMIC_RELAXED,
                                        __HIP_MEMORY_SCOPE_AGENT);
    if (a == gen*32u - 1u) {           // last arriver in this XCD
      unsigned r = __hip_atomic_fetch_add(p.root, 1u, __ATOMIC_RELAXED,
                                          __HIP_MEMORY_SCOPE_AGENT);
      if (r == gen*8u - 1u) {          // last XCD
#pragma unroll
        for (int i = 0; i < 8; ++i)
          __hip_atomic_store(&p.rel[i*16], gen, __ATOMIC_RELAXED,
                             __HIP_MEMORY_SCOPE_AGENT);
      }
    }
    while (__hip_atomic_load(&p.rel[xcd*16], __ATOMIC_RELAXED,
                             __HIP_MEMORY_SCOPE_AGENT) < gen)
      __builtin_amdgcn_s_sleep(1);
  }
  __syncthreads();
}

// ---------------- main cooperative kernel ----------------
// phase0: gates0(256x4096) = A0[t&1] @ W0T^T + b0, fused layer-0 cell.
// 128 jobs, tile 64x128 (bids 0..127). 8 waves 2x4, wave-tile 32x32.
__device__ void phase0(const MP& p, int t, char* smem){
  int bid = blockIdx.x;
  int xcd = bid & 7, local = (bid >> 3) & 3, mt = bid >> 5;
  int nt = xcd*4 + local;               // 0..31
  int m0 = mt*64, n0 = nt*128;
  u16* As = (u16*)smem;                 // [64][LDK]
  u16* Bs = (u16*)smem + 64*LDK;        // [128][LDK]
  const u16* A = p.A0 + (size_t)(t & 1) * BATCH * K0;
  const u16* B = p.W0T;
  int tid = threadIdx.x, lane = tid & 63, wid = tid >> 6;
  int wm = wid >> 2, wn = wid & 3;
  int lrow = lane & 15, kgrp = lane >> 4;
  f32x4 acc00 = {0,0,0,0}, acc01 = {0,0,0,0}, acc10 = {0,0,0,0}, acc11 = {0,0,0,0};
  for (int kt = 0; kt < K0/128; ++kt) {
    int kk0 = kt*128;
    // B: plain cached 16B loads (weights, L2-resident)
    for (int c = tid; c < 2048; c += NT) {
      int r = c >> 4, s = c & 15;
      *(short8*)&Bs[r*LDK + s*8] = *(const short8*)&B[(n0 + r)*K0 + kk0 + s*8];
    }
    // A: coherent 8B loads (cross-block data)
    for (int c = tid; c < 2048; c += NT) {
      int r = c >> 5, s = c & 31;
      *(u64*)((char*)As + r*LDK*2 + s*8) = ald64(&A[(m0 + r)*K0 + kk0 + s*4]);
    }
    __syncthreads();
#pragma unroll
    for (int kk = 0; kk < 4; ++kk) {
      short8 a0 = *(const short8*)&As[(wm*32 + lrow)*LDK + kk*32 + kgrp*8];
      short8 a1 = *(const short8*)&As[(wm*32 + 16 + lrow)*LDK + kk*32 + kgrp*8];
      short8 b0 = *(const short8*)&Bs[(wn*32 + lrow)*LDK + kk*32 + kgrp*8];
      short8 b1 = *(const short8*)&Bs[(wn*32 + 16 + lrow)*LDK + kk*32 + kgrp*8];
      acc00 = __builtin_amdgcn_mfma_f32_16x16x32_bf16(a0, b0, acc00, 0, 0, 0);
      acc01 = __builtin_amdgcn_mfma_f32_16x16x32_bf16(a0, b1, acc01, 0, 0, 0);
      acc10 = __builtin_amdgcn_mfma_f32_16x16x32_bf16(a1, b0, acc10, 0, 0, 0);
      acc11 = __builtin_amdgcn_mfma_f32_16x16x32_bf16(a1, b1, acc11, 0, 0, 0);
    }
    __syncthreads();
  }
  float* gl = (float*)smem;             // [64][132]
#pragma unroll
  for (int r = 0; r < 4; ++r) {
    gl[(wm*32      + kgrp*4 + r)*132 + wn*32      + lrow] = acc00[r];
    gl[(wm*32      + kgrp*4 + r)*132 + wn*32 + 16 + lrow] = acc01[r];
    gl[(wm*32 + 16 + kgrp*4 + r)*132 + wn*32      + lrow] = acc10[r];
    gl[(wm*32 + 16 + kgrp*4 + r)*132 + wn*32 + 16 + lrow] = acc11[r];
  }
  __syncthreads();
  float* c0s = p.out + OFF_C0;
  u16* A0n = p.A0 + (size_t)((t+1) & 1) * BATCH * K0;
  u16* A1c = p.A1 + (size_t)(t & 1) * BATCH * K1;
  for (int e = tid; e < 1024; e += NT) {     // 1024 h-pairs
    int bl = e >> 4, hp = e & 15;
    int b = m0 + bl, h = nt*32 + hp*2;
    float hn[2];
#pragma unroll
    for (int q = 0; q < 2; ++q) {
      int col = (hp*2 + q)*4;
      float gi = gl[bl*132 + col+0] + p.b0[n0 + col+0];
      float gf = gl[bl*132 + col+1] + p.b0[n0 + col+1];
      float go = gl[bl*132 + col+2] + p.b0[n0 + col+2];
      float gc = gl[bl*132 + col+3] + p.b0[n0 + col+3];
      float cp = c0s[b*1024 + h + q];
      float cn = sigm(gf)*cp + sigm(gi)*tanh_(gc);
      hn[q] = sigm(go)*tanh_(cn);
      c0s[b*1024 + h + q] = cn;
      if (t == TS-1) p.out[OFF_H0 + b*1024 + h + q] = hn[q];
    }
    u32 pk = (u32)f2b(hn[0]) | ((u32)f2b(hn[1]) << 16);
    ast32(&A0n[b*K0 + 256 + h], pk);
    ast32(&A1c[b*K1 + h], pk);
  }
}

// phase1: gates1(256x1024) = A1[t&1] @ W1T^T + b1, fused layer-1 cell.
// 64 jobs, tile 64x64 (bids 128..191). 8 waves 2x4, wave-tile 32x16.
__device__ void phase1(const MP& p, int t, char* smem){
  int j = blockIdx.x - 128;
  int xcd = j & 7, local = (j >> 3) & 1, mt = j >> 4;
  int ntp = xcd*2 + local;              // 0..15
  int m0 = mt*64, n0 = ntp*64;
  u16* As = (u16*)smem;                 // [64][LDK]
  u16* Bs = (u16*)smem + 64*LDK;        // [64][LDK]
  const u16* A = p.A1 + (size_t)(t & 1) * BATCH * K1;
  const u16* B = p.W1T;
  int tid = threadIdx.x, lane = tid & 63, wid = tid >> 6;
  int wm = wid >> 2, wn = wid & 3;
  int lrow = lane & 15, kgrp = lane >> 4;
  f32x4 acc0 = {0,0,0,0}, acc1 = {0,0,0,0};
  for (int kt = 0; kt < K1/128; ++kt) {
    int kk0 = kt*128;
    for (int c = tid; c < 1024; c += NT) {
      int r = c >> 4, s = c & 15;
      *(short8*)&Bs[r*LDK + s*8] = *(const short8*)&B[(n0 + r)*K1 + kk0 + s*8];
    }
    for (int c = tid; c < 2048; c += NT) {
      int r = c >> 5, s = c & 31;
      *(u64*)((char*)As + r*LDK*2 + s*8) = ald64(&A[(m0 + r)*K1 + kk0 + s*4]);
    }
    __syncthreads();
#pragma unroll
    for (int kk = 0; kk < 4; ++kk) {
      short8 bv = *(const short8*)&Bs[(wn*16 + lrow)*LDK + kk*32 + kgrp*8];
      short8 a0 = *(const short8*)&As[(wm*32 + lrow)*LDK + kk*32 + kgrp*8];
      short8 a1 = *(const short8*)&As[(wm*32 + 16 + lrow)*LDK + kk*32 + kgrp*8];
      acc0 = __builtin_amdgcn_mfma_f32_16x16x32_bf16(a0, bv, acc0, 0, 0, 0);
      acc1 = __builtin_amdgcn_mfma_f32_16x16x32_bf16(a1, bv, acc1, 0, 0, 0);
    }
    __syncthreads();
  }
  float* gl = (float*)smem;             // [64][68]
#pragma unroll
  for (int r = 0; r < 4; ++r) {
    gl[(wm*32      + kgrp*4 + r)*68 + wn*16 + lrow] = acc0[r];
    gl[(wm*32 + 16 + kgrp*4 + r)*68 + wn*16 + lrow] = acc1[r];
  }
  __syncthreads();
  float* c1s = p.out + OFF_C1;
  u16* A1n = p.A1 + (size_t)((t+1) & 1) * BATCH * K1;
  if (tid < 512) {                      // 512 h-pairs
    int bl = tid >> 3, hp = tid & 7;
    int b = m0 + bl, h = ntp*16 + hp*2;
    float hn[2];
#pragma unroll
    for (int q = 0; q < 2; ++q) {
      int col = (hp*2 + q)*4;
      float gi = gl[bl*68 + col+0] + p.b1[n0 + col+0];
      float gf = gl[bl*68 + col+1] + p.b1[n0 + col+1];
      float go = gl[bl*68 + col+2] + p.b1[n0 + col+2];
      float gc = gl[bl*68 + col+3] + p.b1[n0 + col+3];
      float cp = c1s[b*256 + h + q];
      float cn = sigm(gf)*cp + sigm(gi)*tanh_(gc);
      hn[q] = sigm(go)*tanh_(cn);
      c1s[b*256 + h + q] = cn;
      if (t == TS-1) p.out[OFF_H1 + b*256 + h + q] = hn[q];
    }
    ast32(&A1n[b*K1 + 1024 + h], (u32)f2b(hn[0]) | ((u32)f2b(hn[1]) << 16));
    *(float2*)&p.hseq[((size_t)t*256 + b)*256 + h] = make_float2(hn[0], hn[1]);
  }
}

// spare blocks (192..255): pre-stage x_{tn} into A0 panel[tn&1]
__device__ void stage_x(const MP& p, int tn){
  int j = blockIdx.x - 192;             // 0..63
  u16* A0n = p.A0 + (size_t)(tn & 1) * BATCH * K0;
  int i = j*NT + threadIdx.x;           // 0..32767 f-pairs
  int b = i >> 7, fp = i & 127;
  const float* xs = &p.x[(size_t)b*32768 + tn*256 + fp*2];
  u32 pk = (u32)f2b(xs[0]) | ((u32)f2b(xs[1]) << 16);
  ast32(&A0n[b*K0 + fp*2], pk);
}

__global__ __launch_bounds__(NT) void k_main(MP p){
  __shared__ __attribute__((aligned(16))) char smem[(64+128)*LDK*2];  // 52224 B
  int bid = blockIdx.x;
  for (int s = 0; s < TS; ++s) {
    if (bid < 128)        phase0(p, s, smem);                  // layer0 @ t=s
    else if (bid < 192) { if (s >= 1) phase1(p, s-1, smem); }  // layer1 @ t=s-1
    else                { if (s+1 < TS) stage_x(p, s+1); }
    gbar(p, (unsigned)(s+1));
  }
  if (bid >= 128 && bid < 192) phase1(p, TS-1, smem);          // pipeline tail
}

// ---------------- final projection ----------------
__global__ void k_final(const float* __restrict__ hseq, const float* __restrict__ Wout,
                        const float* __restrict__ bout, float* __restrict__ out){
  __shared__ float Ws[1536];
  __shared__ float bs[12];
  for (int i = threadIdx.x; i < 1536; i += 256) Ws[i] = Wout[i];
  if (threadIdx.x < 12) bs[threadIdx.x] = bout[threadIdx.x];
  __syncthreads();
  int gid = blockIdx.x*256 + threadIdx.x;
  int b = gid >> 8, ii = gid & 255;
  const float* src = hseq + ((size_t)(ii >> 1)*256 + b)*256 + (ii & 1)*128;
  float acc[12];
#pragma unroll
  for (int k = 0; k < 12; ++k) acc[k] = bs[k];
  for (int j = 0; j < 128; j += 4) {
    float4 v = *(const float4*)&src[j];
#pragma unroll
    for (int k = 0; k < 12; ++k)
      acc[k] += v.x*Ws[(j+0)*12+k] + v.y*Ws[(j+1)*12+k] + v.z*Ws[(j+2)*12+k] + v.w*Ws[(j+3)*12+k];
  }
  float* dst = out + (size_t)b*3072 + ii*12;
#pragma unroll
  for (int k = 0; k < 12; ++k) dst[k] = acc[k];
}

extern "C" void kernel_launch(void* const* d_in, const int* in_sizes, int n_in,
                              void* d_out, int out_size, void* d_ws, size_t ws_size,
                              hipStream_t stream) {
  if (ws_size < (size_t)WS_NEED) return;
  const float* x    = (const float*)d_in[0];
  const float* Wx0  = (const float*)d_in[1];
  const float* bx0  = (const float*)d_in[2];
  const float* Wh0  = (const float*)d_in[3];
  const float* bh0  = (const float*)d_in[4];
  const float* Wx1  = (const float*)d_in[5];
  const float* bx1  = (const float*)d_in[6];
  const float* Wh1  = (const float*)d_in[7];
  const float* bh1  = (const float*)d_in[8];
  const float* Wout = (const float*)d_in[9];
  const float* bout = (const float*)d_in[10];

  char* ws = (char*)d_ws;
  u16*   W0T  = (u16*)  (ws + WSO_W0T);
  u16*   W1T  = (u16*)  (ws + WSO_W1T);
  float* b0   = (float*)(ws + WSO_B0);
  float* b1   = (float*)(ws + WSO_B1);
  u16*   A0   = (u16*)  (ws + WSO_A0);
  u16*   A1   = (u16*)  (ws + WSO_A1);
  float* hseq = (float*)(ws + WSO_HSEQ);
  unsigned* barbase = (unsigned*)(ws + WSO_BAR);
  float* out = (float*)d_out;

  k_pack<<<dim3(20,16,4), 256, 0, stream>>>(Wx0, Wh0, W0T, 256, 1024);
  k_pack<<<dim3(20, 4,4), 256, 0, stream>>>(Wx1, Wh1, W1T, 1024, 256);
  k_bias<<<16, 256, 0, stream>>>(bx0, bh0, bx1, bh1, b0, b1);
  k_init<<<2560, 256, 0, stream>>>(A0, A1, out, barbase);
  k_init2<<<256, 256, 0, stream>>>(x, A0);

  MP p;
  p.x = x; p.W0T = W0T; p.W1T = W1T; p.b0 = b0; p.b1 = b1;
  p.A0 = A0; p.A1 = A1; p.hseq = hseq; p.out = out;
  p.arr  = barbase;
  p.root = barbase + 8*16;
  p.rel  = barbase + 8*16 + 16;
  void* kargs[] = { (void*)&p };
  hipLaunchCooperativeKernel((const void*)k_main, dim3(NB), dim3(NT), kargs, 0, stream);

  k_final<<<256, 256, 0, stream>>>(hseq, Wout, bout, out);
}

// Round 5
// 1777.514 us; speedup vs baseline: 9.4236x; 1.9962x over previous
//
#include <hip/hip_runtime.h>
#include <hip/hip_bf16.h>

typedef unsigned short u16;
typedef unsigned int u32;
typedef unsigned long long u64;
typedef __attribute__((ext_vector_type(8))) short short8;
typedef __attribute__((ext_vector_type(4))) float f32x4;

#define NB 256          // main kernel grid blocks
#define NT 512          // threads (8 waves)
#define TS 128
#define BATCH 256
#define LDK 136         // 128 + 8 bf16 pad

// d_out offsets (floats): [out][h_n0][h_n1][c_n0][c_n1]
#define OFF_H0  786432
#define OFF_H1  1048576
#define OFF_C0  1114112
#define OFF_C1  1376256

// ws offsets (bytes)
#define WSO_W0T  0
#define WSO_W1T  (WSO_W0T + 4096*1280*2)
#define WSO_B0   (WSO_W1T + 1024*1280*2)
#define WSO_B1   (WSO_B0  + 4096*4)
#define WSO_H0   (WSO_B1  + 1024*4)            // 2 x [256][1024] bf16
#define WSO_H1   (WSO_H0  + 2*256*1024*2)      // 2 x [256][256]  bf16
#define WSO_X    (WSO_H1  + 2*256*256*2)       // 2 x [256][256]  bf16
#define WSO_HSEQ (WSO_X   + 2*256*256*2)
#define WSO_BAR  (WSO_HSEQ + 128*256*256*4)
#define BAR_DW   (8*16)   // arr[4] + rel[4], 64B-strided
#define WS_NEED  (WSO_BAR + BAR_DW*4)

struct MP {
  const float* x;
  const u16*  W0T;      // [4096][1280] bf16, row n=h*4+g
  const u16*  W1T;      // [1024][1280] bf16
  const float* b0;      // [4096]
  const float* b1;      // [1024]
  u16*  H0;             // 2 x [256][1024] h0 state panels
  u16*  H1;             // 2 x [256][256]
  u16*  X;              // 2 x [256][256] x_t bf16 panels
  float* hseq;          // [128][256][256]
  float* out;
  unsigned* bar;        // arr[g]=bar+g*16, rel[g]=bar+(4+g)*16
};

__device__ __forceinline__ float sigm(float x){ return 1.f/(1.f+__expf(-x)); }
__device__ __forceinline__ float tanh_(float x){
  float t = __expf(-2.f*fabsf(x));
  float r = (1.f - t)/(1.f + t);
  return x < 0.f ? -r : r;
}
__device__ __forceinline__ u16 f2b(float v){
  __hip_bfloat16 h = __float2bfloat16(v);
  return *reinterpret_cast<u16*>(&h);
}
// coherent (sc1, no-fence) 4B store for cross-block data
__device__ __forceinline__ void ast32(u16* p, u32 v){
  __hip_atomic_store((u32*)p, v, __ATOMIC_RELAXED, __HIP_MEMORY_SCOPE_AGENT);
}
// wide pipelined loads via inline asm; CLOAD = coherent (bypass stale L2)
#define CLOAD(dst, ptr) asm volatile("global_load_dwordx4 %0, %1, off sc0 sc1" : "=v"(dst) : "v"(ptr) : "memory")
#define PLOAD(dst, ptr) asm volatile("global_load_dwordx4 %0, %1, off" : "=v"(dst) : "v"(ptr) : "memory")
__device__ __forceinline__ void cwait(){
  asm volatile("s_waitcnt vmcnt(0)" ::: "memory");
  __builtin_amdgcn_sched_barrier(0);
}

// ---------------- prologue kernels ----------------

__global__ void k_pack(const float* __restrict__ Wx, const float* __restrict__ Wh,
                       u16* __restrict__ dst, int KX, int H){
  __shared__ float tile[64][65];
  int k0 = blockIdx.x*64, h0 = blockIdx.y*64, g = blockIdx.z;
  int tid = threadIdx.x;
  int c = tid & 63;
  for (int r = tid >> 6; r < 64; r += 4) {
    int k = k0 + r;
    float v = (k < KX) ? Wx[((size_t)g*KX + k)*H + h0 + c]
                       : Wh[((size_t)g*H + (k-KX))*H + h0 + c];
    tile[r][c] = v;
  }
  __syncthreads();
  for (int cc = tid; cc < 512; cc += 256) {
    int hl = cc >> 3, seg = cc & 7;
    union { u16 u[8]; short8 v; } pk;
#pragma unroll
    for (int j = 0; j < 8; ++j) pk.u[j] = f2b(tile[seg*8 + j][hl]);
    *(short8*)&dst[((size_t)(h0+hl)*4 + g)*1280 + k0 + seg*8] = pk.v;
  }
}

__global__ void k_bias(const float* __restrict__ bx0, const float* __restrict__ bh0,
                       const float* __restrict__ bx1, const float* __restrict__ bh1,
                       float* __restrict__ b0, float* __restrict__ b1){
  int n = blockIdx.x*256 + threadIdx.x;
  if (n < 4096) { int h = n >> 2, g = n & 3; b0[n] = bx0[g*1024 + h] + bh0[g*1024 + h]; }
  if (n < 1024) { int h = n >> 2, g = n & 3; b1[n] = bx1[g*256 + h] + bh1[g*256 + h]; }
}

__global__ void k_init(u16* __restrict__ H0, u16* __restrict__ H1,
                       float* __restrict__ out, unsigned* __restrict__ barbase){
  int i = blockIdx.x*256 + threadIdx.x;    // grid 3072*256 = 786432
  if (i < 524288) H0[i] = 0;
  if (i < 131072) H1[i] = 0;
  if (i < 262144) out[OFF_C0 + i] = 0.f;
  if (i < 65536)  out[OFF_C1 + i] = 0.f;
  if (i < BAR_DW) barbase[i] = 0u;
}

__global__ void k_init2(const float* __restrict__ x, u16* __restrict__ X0){
  int i = blockIdx.x*256 + threadIdx.x;          // 65536
  int b = i >> 8, f = i & 255;
  X0[b*256 + f] = f2b(x[(size_t)b*32768 + f]);   // x[:,0,:]
}

// ------------- per-group barrier (64 arrivers, relaxed, no fences) --------
__device__ __forceinline__ void gbar(unsigned* arr, unsigned* rel, unsigned gen){
  __syncthreads();
  if (threadIdx.x == 0) {
    unsigned a = __hip_atomic_fetch_add(arr, 1u, __ATOMIC_RELAXED,
                                        __HIP_MEMORY_SCOPE_AGENT);
    if (a == gen*64u - 1u)
      __hip_atomic_store(rel, gen, __ATOMIC_RELAXED, __HIP_MEMORY_SCOPE_AGENT);
    while (__hip_atomic_load(rel, __ATOMIC_RELAXED,
                             __HIP_MEMORY_SCOPE_AGENT) < gen)
      __builtin_amdgcn_s_sleep(1);
  }
  __syncthreads();
}

// ---------------- main cooperative kernel ----------------
// phase0: gates0(256x4096) = [X(t)|H0(t)](256x1280) @ W0T^T + b0, fused cell.
// 128 blocks (grp=bid>>5), tile 64x128. 8 waves 2x4, wave-tile 32x32.
__device__ void phase0(const MP& p, int t, char* smem){
  int bid = blockIdx.x;
  int xcd = bid & 7, local = (bid >> 3) & 3, mt = bid >> 5;
  int nt = xcd*4 + local;               // 0..31
  int m0 = mt*64, n0 = nt*128;
  u16* As = (u16*)smem;                 // [64][LDK]
  u16* Bs = (u16*)smem + 64*LDK;        // [128][LDK]
  const u16* Xp = p.X  + (size_t)(t & 1) * BATCH * 256;
  const u16* Hp = p.H0 + (size_t)(t & 1) * BATCH * 1024;
  const u16* W  = p.W0T;
  int tid = threadIdx.x, lane = tid & 63, wid = tid >> 6;
  int wm = wid >> 2, wn = wid & 3;
  int lrow = lane & 15, kgrp = lane >> 4;
  int ar = tid >> 4, as = tid & 15;     // staging row/seg
  short8 ra0, ra1, rb0, rb1, rb2, rb3;
  f32x4 acc00 = {0,0,0,0}, acc01 = {0,0,0,0}, acc10 = {0,0,0,0}, acc11 = {0,0,0,0};

  auto issue = [&](int kt){
    const u16* sb; int str, kof;
    if (kt < 2) { sb = Xp; str = 256;  kof = kt*128; }
    else        { sb = Hp; str = 1024; kof = (kt-2)*128; }
    CLOAD(ra0, sb + (size_t)(m0+ar)*str + kof + as*8);
    CLOAD(ra1, sb + (size_t)(m0+ar+32)*str + kof + as*8);
    const u16* wb = W + (size_t)n0*1280 + kt*128 + as*8;
    PLOAD(rb0, wb + (size_t)(ar     )*1280);
    PLOAD(rb1, wb + (size_t)(ar + 32)*1280);
    PLOAD(rb2, wb + (size_t)(ar + 64)*1280);
    PLOAD(rb3, wb + (size_t)(ar + 96)*1280);
  };

  issue(0);
  for (int kt = 0; kt < 10; ++kt) {
    cwait();
    __syncthreads();                    // prev MFMA done reading LDS
    *(short8*)&As[ ar      *LDK + as*8] = ra0;
    *(short8*)&As[(ar + 32)*LDK + as*8] = ra1;
    *(short8*)&Bs[ ar      *LDK + as*8] = rb0;
    *(short8*)&Bs[(ar + 32)*LDK + as*8] = rb1;
    *(short8*)&Bs[(ar + 64)*LDK + as*8] = rb2;
    *(short8*)&Bs[(ar + 96)*LDK + as*8] = rb3;
    __syncthreads();
    if (kt < 9) issue(kt+1);            // hide next-tile latency under MFMA
#pragma unroll
    for (int kk = 0; kk < 4; ++kk) {
      short8 a0 = *(const short8*)&As[(wm*32 + lrow)*LDK + kk*32 + kgrp*8];
      short8 a1 = *(const short8*)&As[(wm*32 + 16 + lrow)*LDK + kk*32 + kgrp*8];
      short8 b0 = *(const short8*)&Bs[(wn*32 + lrow)*LDK + kk*32 + kgrp*8];
      short8 b1 = *(const short8*)&Bs[(wn*32 + 16 + lrow)*LDK + kk*32 + kgrp*8];
      acc00 = __builtin_amdgcn_mfma_f32_16x16x32_bf16(a0, b0, acc00, 0, 0, 0);
      acc01 = __builtin_amdgcn_mfma_f32_16x16x32_bf16(a0, b1, acc01, 0, 0, 0);
      acc10 = __builtin_amdgcn_mfma_f32_16x16x32_bf16(a1, b0, acc10, 0, 0, 0);
      acc11 = __builtin_amdgcn_mfma_f32_16x16x32_bf16(a1, b1, acc11, 0, 0, 0);
    }
  }
  __syncthreads();
  float* gl = (float*)smem;             // [64][132]
#pragma unroll
  for (int r = 0; r < 4; ++r) {
    gl[(wm*32      + kgrp*4 + r)*132 + wn*32      + lrow] = acc00[r];
    gl[(wm*32      + kgrp*4 + r)*132 + wn*32 + 16 + lrow] = acc01[r];
    gl[(wm*32 + 16 + kgrp*4 + r)*132 + wn*32      + lrow] = acc10[r];
    gl[(wm*32 + 16 + kgrp*4 + r)*132 + wn*32 + 16 + lrow] = acc11[r];
  }
  __syncthreads();
  float* c0s = p.out + OFF_C0;
  u16* H0n = p.H0 + (size_t)((t+1) & 1) * BATCH * 1024;
  for (int e = tid; e < 1024; e += NT) {     // 1024 h-pairs
    int bl = e >> 4, hp = e & 15;
    int b = m0 + bl, h = nt*32 + hp*2;
    float hn[2];
#pragma unroll
    for (int q = 0; q < 2; ++q) {
      int col = (hp*2 + q)*4;
      float gi = gl[bl*132 + col+0] + p.b0[n0 + col+0];
      float gf = gl[bl*132 + col+1] + p.b0[n0 + col+1];
      float go = gl[bl*132 + col+2] + p.b0[n0 + col+2];
      float gc = gl[bl*132 + col+3] + p.b0[n0 + col+3];
      float cp = c0s[b*1024 + h + q];
      float cn = sigm(gf)*cp + sigm(gi)*tanh_(gc);
      hn[q] = sigm(go)*tanh_(cn);
      c0s[b*1024 + h + q] = cn;
      if (t == TS-1) p.out[OFF_H0 + b*1024 + h + q] = hn[q];
    }
    ast32(&H0n[b*1024 + h], (u32)f2b(hn[0]) | ((u32)f2b(hn[1]) << 16));
  }
}

// phase1: gates1(256x1024) = [H0(t)|H1(t-1... wait: H1 parity t&1] @ W1T^T + b1.
// 64 blocks (grp=(bid-128)>>4), tile 64x64. 8 waves 2x4, wave-tile 32x16.
__device__ void phase1(const MP& p, int t, char* smem){
  int j = blockIdx.x - 128;
  int xcd = j & 7, local = (j >> 3) & 1, mt = j >> 4;
  int ntp = xcd*2 + local;              // 0..15
  int m0 = mt*64, n0 = ntp*64;
  u16* As = (u16*)smem;                 // [64][LDK]
  u16* Bs = (u16*)smem + 64*LDK;        // [64][LDK]
  const u16* Hp  = p.H0 + (size_t)((t+1) & 1) * BATCH * 1024;  // h0(t)
  const u16* H1p = p.H1 + (size_t)(t & 1) * BATCH * 256;       // h1(t-1)
  const u16* W   = p.W1T;
  int tid = threadIdx.x, lane = tid & 63, wid = tid >> 6;
  int wm = wid >> 2, wn = wid & 3;
  int lrow = lane & 15, kgrp = lane >> 4;
  int ar = tid >> 4, as = tid & 15;
  short8 ra0, ra1, rb0, rb1;
  f32x4 acc0 = {0,0,0,0}, acc1 = {0,0,0,0};

  auto issue = [&](int kt){
    const u16* sb; int str, kof;
    if (kt < 8) { sb = Hp;  str = 1024; kof = kt*128; }
    else        { sb = H1p; str = 256;  kof = (kt-8)*128; }
    CLOAD(ra0, sb + (size_t)(m0+ar)*str + kof + as*8);
    CLOAD(ra1, sb + (size_t)(m0+ar+32)*str + kof + as*8);
    const u16* wb = W + (size_t)n0*1280 + kt*128 + as*8;
    PLOAD(rb0, wb + (size_t)(ar     )*1280);
    PLOAD(rb1, wb + (size_t)(ar + 32)*1280);
  };

  issue(0);
  for (int kt = 0; kt < 10; ++kt) {
    cwait();
    __syncthreads();
    *(short8*)&As[ ar      *LDK + as*8] = ra0;
    *(short8*)&As[(ar + 32)*LDK + as*8] = ra1;
    *(short8*)&Bs[ ar      *LDK + as*8] = rb0;
    *(short8*)&Bs[(ar + 32)*LDK + as*8] = rb1;
    __syncthreads();
    if (kt < 9) issue(kt+1);
#pragma unroll
    for (int kk = 0; kk < 4; ++kk) {
      short8 bv = *(const short8*)&Bs[(wn*16 + lrow)*LDK + kk*32 + kgrp*8];
      short8 a0 = *(const short8*)&As[(wm*32 + lrow)*LDK + kk*32 + kgrp*8];
      short8 a1 = *(const short8*)&As[(wm*32 + 16 + lrow)*LDK + kk*32 + kgrp*8];
      acc0 = __builtin_amdgcn_mfma_f32_16x16x32_bf16(a0, bv, acc0, 0, 0, 0);
      acc1 = __builtin_amdgcn_mfma_f32_16x16x32_bf16(a1, bv, acc1, 0, 0, 0);
    }
  }
  __syncthreads();
  float* gl = (float*)smem;             // [64][68]
#pragma unroll
  for (int r = 0; r < 4; ++r) {
    gl[(wm*32      + kgrp*4 + r)*68 + wn*16 + lrow] = acc0[r];
    gl[(wm*32 + 16 + kgrp*4 + r)*68 + wn*16 + lrow] = acc1[r];
  }
  __syncthreads();
  float* c1s = p.out + OFF_C1;
  u16* H1n = p.H1 + (size_t)((t+1) & 1) * BATCH * 256;
  if (tid < 512) {                      // 512 h-pairs
    int bl = tid >> 3, hp = tid & 7;
    int b = m0 + bl, h = ntp*16 + hp*2;
    float hn[2];
#pragma unroll
    for (int q = 0; q < 2; ++q) {
      int col = (hp*2 + q)*4;
      float gi = gl[bl*68 + col+0] + p.b1[n0 + col+0];
      float gf = gl[bl*68 + col+1] + p.b1[n0 + col+1];
      float go = gl[bl*68 + col+2] + p.b1[n0 + col+2];
      float gc = gl[bl*68 + col+3] + p.b1[n0 + col+3];
      float cp = c1s[b*256 + h + q];
      float cn = sigm(gf)*cp + sigm(gi)*tanh_(gc);
      hn[q] = sigm(go)*tanh_(cn);
      c1s[b*256 + h + q] = cn;
      if (t == TS-1) p.out[OFF_H1 + b*256 + h + q] = hn[q];
    }
    ast32(&H1n[b*256 + h], (u32)f2b(hn[0]) | ((u32)f2b(hn[1]) << 16));
    *(float2*)&p.hseq[((size_t)t*256 + b)*256 + h] = make_float2(hn[0], hn[1]);
  }
}

// stage blocks (192..255, 16 per group): pre-stage x_{tn} into X[tn&1], own m-strip
__device__ void stage_x(const MP& p, int tn){
  int j = blockIdx.x - 192;
  int mt = j >> 4, j2 = j & 15;
  u16* Xn = p.X + (size_t)(tn & 1) * BATCH * 256;
  int idx = j2*NT + threadIdx.x;        // 0..8191 f-pairs for 64 rows
  int bl = idx >> 7, fp = idx & 127;
  int b = mt*64 + bl;
  const float* xs = &p.x[(size_t)b*32768 + tn*256 + fp*2];
  ast32(&Xn[b*256 + fp*2], (u32)f2b(xs[0]) | ((u32)f2b(xs[1]) << 16));
}

__global__ __launch_bounds__(NT) void k_main(MP p){
  __shared__ __attribute__((aligned(16))) char smem[(64+128)*LDK*2];  // 52224 B
  int bid = blockIdx.x;
  int grp = (bid < 128) ? (bid >> 5) : ((bid < 192) ? ((bid-128) >> 4) : ((bid-192) >> 4));
  unsigned* arr = p.bar + grp*16;
  unsigned* rel = p.bar + (4 + grp)*16;
  for (int s = 0; s < TS; ++s) {
    if (bid < 128)        phase0(p, s, smem);                  // layer0 @ t=s
    else if (bid < 192) { if (s >= 1) phase1(p, s-1, smem); }  // layer1 @ t=s-1
    else                { if (s+1 < TS) stage_x(p, s+1); }
    gbar(arr, rel, (unsigned)(s+1));
  }
  if (bid >= 128 && bid < 192) phase1(p, TS-1, smem);          // pipeline tail
}

// ---------------- final projection ----------------
__global__ void k_final(const float* __restrict__ hseq, const float* __restrict__ Wout,
                        const float* __restrict__ bout, float* __restrict__ out){
  __shared__ float Ws[1536];
  __shared__ float bs[12];
  for (int i = threadIdx.x; i < 1536; i += 256) Ws[i] = Wout[i];
  if (threadIdx.x < 12) bs[threadIdx.x] = bout[threadIdx.x];
  __syncthreads();
  int gid = blockIdx.x*256 + threadIdx.x;
  int b = gid >> 8, ii = gid & 255;
  const float* src = hseq + ((size_t)(ii >> 1)*256 + b)*256 + (ii & 1)*128;
  float acc[12];
#pragma unroll
  for (int k = 0; k < 12; ++k) acc[k] = bs[k];
  for (int j = 0; j < 128; j += 4) {
    float4 v = *(const float4*)&src[j];
#pragma unroll
    for (int k = 0; k < 12; ++k)
      acc[k] += v.x*Ws[(j+0)*12+k] + v.y*Ws[(j+1)*12+k] + v.z*Ws[(j+2)*12+k] + v.w*Ws[(j+3)*12+k];
  }
  float* dst = out + (size_t)b*3072 + ii*12;
#pragma unroll
  for (int k = 0; k < 12; ++k) dst[k] = acc[k];
}

extern "C" void kernel_launch(void* const* d_in, const int* in_sizes, int n_in,
                              void* d_out, int out_size, void* d_ws, size_t ws_size,
                              hipStream_t stream) {
  if (ws_size < (size_t)WS_NEED) return;
  const float* x    = (const float*)d_in[0];
  const float* Wx0  = (const float*)d_in[1];
  const float* bx0  = (const float*)d_in[2];
  const float* Wh0  = (const float*)d_in[3];
  const float* bh0  = (const float*)d_in[4];
  const float* Wx1  = (const float*)d_in[5];
  const float* bx1  = (const float*)d_in[6];
  const float* Wh1  = (const float*)d_in[7];
  const float* bh1  = (const float*)d_in[8];
  const float* Wout = (const float*)d_in[9];
  const float* bout = (const float*)d_in[10];

  char* ws = (char*)d_ws;
  u16*   W0T  = (u16*)  (ws + WSO_W0T);
  u16*   W1T  = (u16*)  (ws + WSO_W1T);
  float* b0   = (float*)(ws + WSO_B0);
  float* b1   = (float*)(ws + WSO_B1);
  u16*   H0   = (u16*)  (ws + WSO_H0);
  u16*   H1   = (u16*)  (ws + WSO_H1);
  u16*   X    = (u16*)  (ws + WSO_X);
  float* hseq = (float*)(ws + WSO_HSEQ);
  unsigned* barbase = (unsigned*)(ws + WSO_BAR);
  float* out = (float*)d_out;

  k_pack<<<dim3(20,16,4), 256, 0, stream>>>(Wx0, Wh0, W0T, 256, 1024);
  k_pack<<<dim3(20, 4,4), 256, 0, stream>>>(Wx1, Wh1, W1T, 1024, 256);
  k_bias<<<16, 256, 0, stream>>>(bx0, bh0, bx1, bh1, b0, b1);
  k_init<<<3072, 256, 0, stream>>>(H0, H1, out, barbase);
  k_init2<<<256, 256, 0, stream>>>(x, X);

  MP p;
  p.x = x; p.W0T = W0T; p.W1T = W1T; p.b0 = b0; p.b1 = b1;
  p.H0 = H0; p.H1 = H1; p.X = X; p.hseq = hseq; p.out = out;
  p.bar = barbase;
  void* kargs[] = { (void*)&p };
  hipLaunchCooperativeKernel((const void*)k_main, dim3(NB), dim3(NT), kargs, 0, stream);

  k_final<<<256, 256, 0, stream>>>(hseq, Wout, bout, out);
}

// Round 7
// 1755.347 us; speedup vs baseline: 9.5426x; 1.0126x over previous
//
#include <hip/hip_runtime.h>
#include <hip/hip_bf16.h>

typedef unsigned short u16;
typedef unsigned int u32;
typedef unsigned long long u64;
typedef __attribute__((ext_vector_type(8))) short short8;
typedef __attribute__((ext_vector_type(4))) float f32x4;

#define NB 256
#define NT 512          // 8 waves
#define TS 128
#define LDK 136         // 128 + 8 bf16 pad

// d_out offsets (floats): [out][h_n0][h_n1][c_n0][c_n1]
#define OFF_H0  786432
#define OFF_H1  1048576
#define OFF_C0  1114112
#define OFF_C1  1376256

// ws offsets (bytes)
#define WSO_W0F  0                         // 10240 frags x 1KB
#define WSO_W1F  (WSO_W0F + 10485760)      // 2560 frags x 1KB
#define WSO_B0   (WSO_W1F + 2621440)
#define WSO_B1   (WSO_B0  + 16384)
#define WSO_H0   (WSO_B1  + 4096)          // 2 x [256][1024] bf16
#define WSO_H1   (WSO_H0  + 1048576)       // 2 x [256][256]
#define WSO_X    (WSO_H1  + 262144)        // 2 x [256][256]
#define WSO_HSEQ (WSO_X   + 262144)        // [128][256][256] f32
#define WSO_BAR  (WSO_HSEQ + 33554432)
#define BAR_DW   128                       // arr[4] + rel[4], 64B-strided
#define WS_NEED  (WSO_BAR + BAR_DW*4)

struct MP {
  const float* x;
  const u16*  W0F;      // layer0 weights, MFMA-fragment layout
  const u16*  W1F;      // layer1 weights, MFMA-fragment layout
  const float* b0;      // [4096] n=h*4+g
  const float* b1;      // [1024]
  u16*  H0;             // 2 x [256][1024]
  u16*  H1;             // 2 x [256][256]
  u16*  X;              // 2 x [256][256]
  float* hseq;          // [128][256][256]
  float* out;
  unsigned* bar;
};

__device__ __forceinline__ float sigm(float x){ return 1.f/(1.f+__expf(-x)); }
__device__ __forceinline__ float tanh_(float x){
  float t = __expf(-2.f*fabsf(x));
  float r = (1.f - t)/(1.f + t);
  return x < 0.f ? -r : r;
}
__device__ __forceinline__ u16 f2b(float v){
  __hip_bfloat16 h = __float2bfloat16(v);
  return *reinterpret_cast<u16*>(&h);
}
__device__ __forceinline__ void ast32(u16* p, u32 v){
  __hip_atomic_store((u32*)p, v, __ATOMIC_RELAXED, __HIP_MEMORY_SCOPE_AGENT);
}
__device__ __forceinline__ f32x4 MF(short8 a, short8 b, f32x4 c){
  return __builtin_amdgcn_mfma_f32_16x16x32_bf16(a, b, c, 0, 0, 0);
}

#define STRX(x) #x
#define PLOADO(dst, ptr, off) asm volatile("global_load_dwordx4 %0, %1, off offset:" STRX(off) : "=v"(dst) : "v"(ptr))
#define CLOADO(dst, ptr, off) asm volatile("global_load_dwordx4 %0, %1, off offset:" STRX(off) " sc0 sc1" : "=v"(dst) : "v"(ptr))
__device__ __forceinline__ void cwait(){
  asm volatile("s_waitcnt vmcnt(0)" ::: "memory");
  __builtin_amdgcn_sched_barrier(0);
}

// ---------------- prologue kernels ----------------

// layer0 frag F = ((nt*10+kt)*4+wn)*8 + nf*4+kk ; lane -> n=(lane&15), k-sub=(lane>>4)*8
__global__ void k_packF0(const float* __restrict__ Wx, const float* __restrict__ Wh,
                         u16* __restrict__ W0F){
  int gid = blockIdx.x*256 + threadIdx.x;       // 655360
  int F = gid >> 6, lane = gid & 63;
  int kk = F & 3, nf = (F >> 2) & 1;
  int r1 = F >> 3, wn = r1 & 3;
  int r2 = r1 >> 2, kt = r2 % 10, nt = r2 / 10; // nt 0..31
  int n = nt*128 + wn*32 + nf*16 + (lane & 15);
  int h = n >> 2, g = n & 3;
  int kb = kt*128 + kk*32 + (lane >> 4)*8;
  union { u16 u[8]; short8 v; } pk;
#pragma unroll
  for (int j = 0; j < 8; ++j) {
    int k = kb + j;
    float v = (k < 256) ? Wx[((size_t)g*256 + k)*1024 + h]
                        : Wh[((size_t)g*1024 + (k-256))*1024 + h];
    pk.u[j] = f2b(v);
  }
  *(short8*)&W0F[(size_t)F*512 + lane*8] = pk.v;
}

// layer1 frag F = ((ntp*10+kt)*4+wn)*4 + kk
__global__ void k_packF1(const float* __restrict__ Wx, const float* __restrict__ Wh,
                         u16* __restrict__ W1F){
  int gid = blockIdx.x*256 + threadIdx.x;       // 163840
  int F = gid >> 6, lane = gid & 63;
  int kk = F & 3;
  int r1 = F >> 2, wn = r1 & 3;
  int r2 = r1 >> 2, kt = r2 % 10, ntp = r2 / 10; // ntp 0..15
  int n = ntp*64 + wn*16 + (lane & 15);
  int h = n >> 2, g = n & 3;
  int kb = kt*128 + kk*32 + (lane >> 4)*8;
  union { u16 u[8]; short8 v; } pk;
#pragma unroll
  for (int j = 0; j < 8; ++j) {
    int k = kb + j;
    float v = (k < 1024) ? Wx[((size_t)g*1024 + k)*256 + h]
                         : Wh[((size_t)g*256 + (k-1024))*256 + h];
    pk.u[j] = f2b(v);
  }
  *(short8*)&W1F[(size_t)F*512 + lane*8] = pk.v;
}

__global__ void k_bias(const float* __restrict__ bx0, const float* __restrict__ bh0,
                       const float* __restrict__ bx1, const float* __restrict__ bh1,
                       float* __restrict__ b0, float* __restrict__ b1){
  int n = blockIdx.x*256 + threadIdx.x;
  if (n < 4096) { int h = n >> 2, g = n & 3; b0[n] = bx0[g*1024 + h] + bh0[g*1024 + h]; }
  if (n < 1024) { int h = n >> 2, g = n & 3; b1[n] = bx1[g*256 + h] + bh1[g*256 + h]; }
}

__global__ void k_init(u16* __restrict__ H0, u16* __restrict__ H1,
                       unsigned* __restrict__ bar){
  int i = blockIdx.x*256 + threadIdx.x;         // 2048 blocks -> 524288
  if (i < 524288) H0[i] = 0;
  if (i < 131072) H1[i] = 0;
  if (i < BAR_DW) bar[i] = 0u;
}

__global__ void k_init2(const float* __restrict__ x, u16* __restrict__ X0){
  int i = blockIdx.x*256 + threadIdx.x;         // 65536
  X0[i] = f2b(x[(size_t)(i >> 8)*32768 + (i & 255)]);
}

// ------------- per-group barrier (64 arrivers, relaxed, no fences) --------
__device__ __forceinline__ void gbar(unsigned* arr, unsigned* rel, unsigned gen){
  __syncthreads();
  if (threadIdx.x == 0) {
    unsigned a = __hip_atomic_fetch_add(arr, 1u, __ATOMIC_RELAXED,
                                        __HIP_MEMORY_SCOPE_AGENT);
    if (a == gen*64u - 1u)
      __hip_atomic_store(rel, gen, __ATOMIC_RELAXED, __HIP_MEMORY_SCOPE_AGENT);
    while (__hip_atomic_load(rel, __ATOMIC_RELAXED,
                             __HIP_MEMORY_SCOPE_AGENT) < gen)
      __builtin_amdgcn_s_sleep(1);
  }
  __syncthreads();
}

// ---------------- phase0: blocks 0..127, tile 64m x 128n, 8 waves 2x4 ------
__device__ void phase0(const MP& p, int t, char* smem, float* c0){
  const int bid = blockIdx.x, tid = threadIdx.x;
  const int xcd = bid & 7, local = (bid >> 3) & 3, grp = bid >> 5;
  const int nt = xcd*4 + local;         // 0..31
  const int m0 = grp*64, n0 = nt*128;
  const int lane = tid & 63, wid = tid >> 6;
  const int wm = wid >> 2, wn = wid & 3;
  const int lrow = lane & 15, kgrp = lane >> 4;
  u16* As = (u16*)smem;                 // [64][LDK]
  const u16* Xp = p.X  + (size_t)(t & 1)*65536;
  const u16* Hp = p.H0 + (size_t)(t & 1)*262144;
  const int ar = tid >> 3, s0 = (tid & 7)*2;
  const u16* bbase = p.W0F + (size_t)(nt*40 + wn)*4096 + lane*8;

  auto aptr = [&](int kt)->const u16* {
    return (kt < 2) ? Xp + (size_t)(m0+ar)*256  + kt*128       + s0*8
                    : Hp + (size_t)(m0+ar)*1024 + (kt-2)*128   + s0*8;
  };
  auto bptr = [&](int kt)->const u16* { return bbase + (size_t)kt*16384; };

  short8 raa0, raa1, rab0, rab1;
  short8 rba0, rba1, rba2, rba3, rba4, rba5, rba6, rba7;
  short8 rbb0, rbb1, rbb2, rbb3, rbb4, rbb5, rbb6, rbb7;
  f32x4 acc00 = {0,0,0,0}, acc01 = {0,0,0,0}, acc10 = {0,0,0,0}, acc11 = {0,0,0,0};

#define ISS_A2(PTR, R0,R1) do{ const u16* _s=(PTR); CLOADO(R0,_s,0); CLOADO(R1,_s,16); }while(0)
#define ST_A2(R0,R1) do{ u16* _d = As + ar*LDK + s0*8; \
    *(short8*)&_d[0]=R0; *(short8*)&_d[8]=R1; }while(0)
#define ISS_B8(PTR, R0,R1,R2,R3,R4,R5,R6,R7) do{ const u16* _s=(PTR); const u16* _s2=_s+2048; \
    PLOADO(R0,_s,0); PLOADO(R1,_s,1024); PLOADO(R2,_s,2048); PLOADO(R3,_s,3072); \
    PLOADO(R4,_s2,0); PLOADO(R5,_s2,1024); PLOADO(R6,_s2,2048); PLOADO(R7,_s2,3072); }while(0)
#define MFMA_P0(B0,B1,B2,B3,B4,B5,B6,B7) do{ short8 a0, a1; \
    a0 = *(const short8*)&As[(wm*32      + lrow)*LDK +  0 + kgrp*8]; \
    a1 = *(const short8*)&As[(wm*32 + 16 + lrow)*LDK +  0 + kgrp*8]; \
    acc00 = MF(a0,B0,acc00); acc01 = MF(a0,B4,acc01); acc10 = MF(a1,B0,acc10); acc11 = MF(a1,B4,acc11); \
    a0 = *(const short8*)&As[(wm*32      + lrow)*LDK + 32 + kgrp*8]; \
    a1 = *(const short8*)&As[(wm*32 + 16 + lrow)*LDK + 32 + kgrp*8]; \
    acc00 = MF(a0,B1,acc00); acc01 = MF(a0,B5,acc01); acc10 = MF(a1,B1,acc10); acc11 = MF(a1,B5,acc11); \
    a0 = *(const short8*)&As[(wm*32      + lrow)*LDK + 64 + kgrp*8]; \
    a1 = *(const short8*)&As[(wm*32 + 16 + lrow)*LDK + 64 + kgrp*8]; \
    acc00 = MF(a0,B2,acc00); acc01 = MF(a0,B6,acc01); acc10 = MF(a1,B2,acc10); acc11 = MF(a1,B6,acc11); \
    a0 = *(const short8*)&As[(wm*32      + lrow)*LDK + 96 + kgrp*8]; \
    a1 = *(const short8*)&As[(wm*32 + 16 + lrow)*LDK + 96 + kgrp*8]; \
    acc00 = MF(a0,B3,acc00); acc01 = MF(a0,B7,acc01); acc10 = MF(a1,B3,acc10); acc11 = MF(a1,B7,acc11); }while(0)

  ISS_A2(aptr(0), raa0,raa1);
  ISS_B8(bptr(0), rba0,rba1,rba2,rba3,rba4,rba5,rba6,rba7);
  for (int k2 = 0; k2 < 5; ++k2) {
    const int kto = 2*k2 + 1;
    // even sub-iter
    cwait();                 // raa (A tile) + rba (B frags) ready
    __syncthreads();         // prior MFMA reads of As done
    ST_A2(raa0,raa1);
    __syncthreads();         // A tile visible (drains lgkm)
    ISS_A2(aptr(kto), rab0,rab1);
    ISS_B8(bptr(kto), rbb0,rbb1,rbb2,rbb3,rbb4,rbb5,rbb6,rbb7);
    MFMA_P0(rba0,rba1,rba2,rba3,rba4,rba5,rba6,rba7);
    // odd sub-iter
    cwait();
    __syncthreads();
    ST_A2(rab0,rab1);
    __syncthreads();
    if (kto < 9) {
      ISS_A2(aptr(kto+1), raa0,raa1);
      ISS_B8(bptr(kto+1), rba0,rba1,rba2,rba3,rba4,rba5,rba6,rba7);
    }
    MFMA_P0(rbb0,rbb1,rbb2,rbb3,rbb4,rbb5,rbb6,rbb7);
  }
  __syncthreads();           // all MFMA LDS reads done before gl aliasing

  float* gl = (float*)smem;  // [64][132]
#pragma unroll
  for (int r = 0; r < 4; ++r) {
    gl[(wm*32      + kgrp*4 + r)*132 + wn*32      + lrow] = acc00[r];
    gl[(wm*32      + kgrp*4 + r)*132 + wn*32 + 16 + lrow] = acc01[r];
    gl[(wm*32 + 16 + kgrp*4 + r)*132 + wn*32      + lrow] = acc10[r];
    gl[(wm*32 + 16 + kgrp*4 + r)*132 + wn*32 + 16 + lrow] = acc11[r];
  }
  __syncthreads();
  u16* H0n = p.H0 + (size_t)((t+1) & 1)*262144;
#pragma unroll
  for (int rep = 0; rep < 2; ++rep) {
    int e = tid + rep*NT;
    int bl = e >> 4, hp = e & 15;
    int b = m0 + bl, h = nt*32 + hp*2;
    float hn[2];
#pragma unroll
    for (int q = 0; q < 2; ++q) {
      int col = (hp*2 + q)*4;
      float gi = gl[bl*132 + col+0] + p.b0[n0 + col+0];
      float gf = gl[bl*132 + col+1] + p.b0[n0 + col+1];
      float go = gl[bl*132 + col+2] + p.b0[n0 + col+2];
      float gc = gl[bl*132 + col+3] + p.b0[n0 + col+3];
      float cn = sigm(gf)*c0[rep*2+q] + sigm(gi)*tanh_(gc);
      hn[q] = sigm(go)*tanh_(cn);
      c0[rep*2+q] = cn;
      if (t == TS-1) {
        p.out[OFF_H0 + (size_t)b*1024 + h + q] = hn[q];
        p.out[OFF_C0 + (size_t)b*1024 + h + q] = cn;
      }
    }
    ast32(H0n + (size_t)b*1024 + h, (u32)f2b(hn[0]) | ((u32)f2b(hn[1]) << 16));
  }
}

// ---------------- phase1: blocks 128..191, tile 64m x 64n, 8 waves 2x4 -----
__device__ void phase1(const MP& p, int t, char* smem, float* c1){
  const int tid = threadIdx.x;
  const int j = blockIdx.x - 128;
  const int xcd = j & 7, local = (j >> 3) & 1, grp = j >> 4;
  const int ntp = xcd*2 + local;        // 0..15
  const int m0 = grp*64, n0 = ntp*64;
  const int lane = tid & 63, wid = tid >> 6;
  const int wm = wid >> 2, wn = wid & 3;
  const int lrow = lane & 15, kgrp = lane >> 4;
  u16* As = (u16*)smem;                 // [64][LDK]
  const u16* Hp  = p.H0 + (size_t)((t+1) & 1)*262144;  // h0(t)
  const u16* H1p = p.H1 + (size_t)(t & 1)*65536;       // h1(t-1)
  const int ar = tid >> 3, s0 = (tid & 7)*2;
  const u16* bbase = p.W1F + (size_t)(ntp*40 + wn)*2048 + lane*8;

  auto aptr = [&](int kt)->const u16* {
    return (kt < 8) ? Hp  + (size_t)(m0+ar)*1024 + kt*128     + s0*8
                    : H1p + (size_t)(m0+ar)*256  + (kt-8)*128 + s0*8;
  };
  auto bptr = [&](int kt)->const u16* { return bbase + (size_t)kt*8192; };

  short8 raa0, raa1, rab0, rab1;
  short8 rba0, rba1, rba2, rba3, rbb0, rbb1, rbb2, rbb3;
  f32x4 acc0 = {0,0,0,0}, acc1 = {0,0,0,0};

#define ISS_B4(PTR, R0,R1,R2,R3) do{ const u16* _s=(PTR); \
    PLOADO(R0,_s,0); PLOADO(R1,_s,1024); PLOADO(R2,_s,2048); PLOADO(R3,_s,3072); }while(0)
#define MFMA_P1(B0,B1,B2,B3) do{ short8 a0, a1; \
    a0 = *(const short8*)&As[(wm*32      + lrow)*LDK +  0 + kgrp*8]; \
    a1 = *(const short8*)&As[(wm*32 + 16 + lrow)*LDK +  0 + kgrp*8]; \
    acc0 = MF(a0,B0,acc0); acc1 = MF(a1,B0,acc1); \
    a0 = *(const short8*)&As[(wm*32      + lrow)*LDK + 32 + kgrp*8]; \
    a1 = *(const short8*)&As[(wm*32 + 16 + lrow)*LDK + 32 + kgrp*8]; \
    acc0 = MF(a0,B1,acc0); acc1 = MF(a1,B1,acc1); \
    a0 = *(const short8*)&As[(wm*32      + lrow)*LDK + 64 + kgrp*8]; \
    a1 = *(const short8*)&As[(wm*32 + 16 + lrow)*LDK + 64 + kgrp*8]; \
    acc0 = MF(a0,B2,acc0); acc1 = MF(a1,B2,acc1); \
    a0 = *(const short8*)&As[(wm*32      + lrow)*LDK + 96 + kgrp*8]; \
    a1 = *(const short8*)&As[(wm*32 + 16 + lrow)*LDK + 96 + kgrp*8]; \
    acc0 = MF(a0,B3,acc0); acc1 = MF(a1,B3,acc1); }while(0)

  ISS_A2(aptr(0), raa0,raa1);
  ISS_B4(bptr(0), rba0,rba1,rba2,rba3);
  for (int k2 = 0; k2 < 5; ++k2) {
    const int kto = 2*k2 + 1;
    cwait();
    __syncthreads();
    ST_A2(raa0,raa1);
    __syncthreads();
    ISS_A2(aptr(kto), rab0,rab1);
    ISS_B4(bptr(kto), rbb0,rbb1,rbb2,rbb3);
    MFMA_P1(rba0,rba1,rba2,rba3);
    cwait();
    __syncthreads();
    ST_A2(rab0,rab1);
    __syncthreads();
    if (kto < 9) {
      ISS_A2(aptr(kto+1), raa0,raa1);
      ISS_B4(bptr(kto+1), rba0,rba1,rba2,rba3);
    }
    MFMA_P1(rbb0,rbb1,rbb2,rbb3);
  }
  __syncthreads();

  float* gl = (float*)smem;             // [64][68]
#pragma unroll
  for (int r = 0; r < 4; ++r) {
    gl[(wm*32      + kgrp*4 + r)*68 + wn*16 + lrow] = acc0[r];
    gl[(wm*32 + 16 + kgrp*4 + r)*68 + wn*16 + lrow] = acc1[r];
  }
  __syncthreads();
  u16* H1n = p.H1 + (size_t)((t+1) & 1)*65536;
  {
    int bl = tid >> 3, hp = tid & 7;    // 64 b-rows x 8 h-pairs
    int b = m0 + bl, h = ntp*16 + hp*2;
    float hn[2];
#pragma unroll
    for (int q = 0; q < 2; ++q) {
      int col = (hp*2 + q)*4;
      float gi = gl[bl*68 + col+0] + p.b1[n0 + col+0];
      float gf = gl[bl*68 + col+1] + p.b1[n0 + col+1];
      float go = gl[bl*68 + col+2] + p.b1[n0 + col+2];
      float gc = gl[bl*68 + col+3] + p.b1[n0 + col+3];
      float cn = sigm(gf)*c1[q] + sigm(gi)*tanh_(gc);
      hn[q] = sigm(go)*tanh_(cn);
      c1[q] = cn;
      if (t == TS-1) {
        p.out[OFF_H1 + (size_t)b*256 + h + q] = hn[q];
        p.out[OFF_C1 + (size_t)b*256 + h + q] = cn;
      }
    }
    ast32(H1n + (size_t)b*256 + h, (u32)f2b(hn[0]) | ((u32)f2b(hn[1]) << 16));
    *(float2*)&p.hseq[((size_t)t*256 + b)*256 + h] = make_float2(hn[0], hn[1]);
  }
}

// ---------------- stage blocks 192..255: pre-stage x_{tn} ------------------
__device__ void stage_x(const MP& p, int tn){
  int j = blockIdx.x - 192;
  int mt = j >> 4, j2 = j & 15;
  u16* Xn = p.X + (size_t)(tn & 1)*65536;
  int idx = j2*NT + threadIdx.x;        // 0..8191 f-pairs for 64 rows
  int bl = idx >> 7, fp = idx & 127;
  int b = mt*64 + bl;
  const float* xs = &p.x[(size_t)b*32768 + (size_t)tn*256 + fp*2];
  ast32(&Xn[b*256 + fp*2], (u32)f2b(xs[0]) | ((u32)f2b(xs[1]) << 16));
}

__global__ __launch_bounds__(NT) void k_main(MP p){
  __shared__ __attribute__((aligned(16))) char smem[34816];
  float c0[4] = {0.f, 0.f, 0.f, 0.f};
  float c1[2] = {0.f, 0.f};
  const int bid = blockIdx.x;
  const int grp = (bid < 128) ? (bid >> 5)
                : (bid < 192) ? ((bid - 128) >> 4)
                              : ((bid - 192) >> 4);
  unsigned* arr = p.bar + grp*16;
  unsigned* rel = p.bar + (4 + grp)*16;
  for (int s = 0; s < TS; ++s) {
    if (bid < 128)        phase0(p, s, smem, c0);                  // layer0 @ t=s
    else if (bid < 192) { if (s >= 1) phase1(p, s-1, smem, c1); }  // layer1 @ t=s-1
    else                { if (s+1 < TS) stage_x(p, s+1); }
    gbar(arr, rel, (unsigned)(s + 1));
  }
  if (bid >= 128 && bid < 192) phase1(p, TS-1, smem, c1);          // pipeline tail
}

// ---------------- final projection ----------------
__global__ void k_final(const float* __restrict__ hseq, const float* __restrict__ Wout,
                        const float* __restrict__ bout, float* __restrict__ out){
  __shared__ float Ws[1536];
  __shared__ float bs[12];
  for (int i = threadIdx.x; i < 1536; i += 256) Ws[i] = Wout[i];
  if (threadIdx.x < 12) bs[threadIdx.x] = bout[threadIdx.x];
  __syncthreads();
  int gid = blockIdx.x*256 + threadIdx.x;
  int b = gid >> 8, ii = gid & 255;
  const float* src = hseq + ((size_t)(ii >> 1)*256 + b)*256 + (ii & 1)*128;
  float acc[12];
#pragma unroll
  for (int k = 0; k < 12; ++k) acc[k] = bs[k];
  for (int jj = 0; jj < 128; jj += 4) {
    float4 v = *(const float4*)&src[jj];
#pragma unroll
    for (int k = 0; k < 12; ++k)
      acc[k] += v.x*Ws[(jj+0)*12+k] + v.y*Ws[(jj+1)*12+k] + v.z*Ws[(jj+2)*12+k] + v.w*Ws[(jj+3)*12+k];
  }
  float* dst = out + (size_t)b*3072 + ii*12;
#pragma unroll
  for (int k = 0; k < 12; ++k) dst[k] = acc[k];
}

extern "C" void kernel_launch(void* const* d_in, const int* in_sizes, int n_in,
                              void* d_out, int out_size, void* d_ws, size_t ws_size,
                              hipStream_t stream) {
  if (ws_size < (size_t)WS_NEED) return;
  const float* x    = (const float*)d_in[0];
  const float* Wx0  = (const float*)d_in[1];
  const float* bx0  = (const float*)d_in[2];
  const float* Wh0  = (const float*)d_in[3];
  const float* bh0  = (const float*)d_in[4];
  const float* Wx1  = (const float*)d_in[5];
  const float* bx1  = (const float*)d_in[6];
  const float* Wh1  = (const float*)d_in[7];
  const float* bh1  = (const float*)d_in[8];
  const float* Wout = (const float*)d_in[9];
  const float* bout = (const float*)d_in[10];

  char* ws = (char*)d_ws;
  u16*   W0F  = (u16*)  (ws + WSO_W0F);
  u16*   W1F  = (u16*)  (ws + WSO_W1F);
  float* b0   = (float*)(ws + WSO_B0);
  float* b1   = (float*)(ws + WSO_B1);
  u16*   H0   = (u16*)  (ws + WSO_H0);
  u16*   H1   = (u16*)  (ws + WSO_H1);
  u16*   X    = (u16*)  (ws + WSO_X);
  float* hseq = (float*)(ws + WSO_HSEQ);
  unsigned* bar = (unsigned*)(ws + WSO_BAR);
  float* out = (float*)d_out;

  k_packF0<<<2560, 256, 0, stream>>>(Wx0, Wh0, W0F);
  k_packF1<<<640, 256, 0, stream>>>(Wx1, Wh1, W1F);
  k_bias<<<16, 256, 0, stream>>>(bx0, bh0, bx1, bh1, b0, b1);
  k_init<<<2048, 256, 0, stream>>>(H0, H1, bar);
  k_init2<<<256, 256, 0, stream>>>(x, X);

  MP p;
  p.x = x; p.W0F = W0F; p.W1F = W1F; p.b0 = b0; p.b1 = b1;
  p.H0 = H0; p.H1 = H1; p.X = X; p.hseq = hseq; p.out = out; p.bar = bar;
  void* kargs[] = { (void*)&p };
  hipLaunchCooperativeKernel((const void*)k_main, dim3(NB), dim3(NT), kargs, 0, stream);

  k_final<<<256, 256, 0, stream>>>(hseq, Wout, bout, out);
}